// Round 8
// baseline (347.242 us; speedup 1.0000x reference)
//
#include <hip/hip_runtime.h>
#include <hip/hip_fp16.h>

typedef float fv4 __attribute__((ext_vector_type(4)));
using hf8   = __attribute__((ext_vector_type(8))) _Float16;  // 8 fp16 = 4 VGPRs (MFMA A/B frag)
using f32x4 = __attribute__((ext_vector_type(4))) float;     // MFMA C/D frag
using u32x4 = __attribute__((ext_vector_type(4))) unsigned;
using u32x2 = __attribute__((ext_vector_type(2))) unsigned;

#define HDIM 64

// fp32 -> fp16 bits (RNE)
__device__ __forceinline__ unsigned short f16r(float f) {
    return __half_as_ushort(__float2half(f));
}
__device__ __forceinline__ float hs2f(unsigned short s) {
    return __half2float(__ushort_as_half(s));
}
// packed fp16: relu(u+v) on 2 channels in one reg (v_pk_add_f16 + v_pk_max_f16)
__device__ __forceinline__ unsigned addrelu2(unsigned ua, unsigned va) {
    unsigned s, r;
    asm("v_pk_add_f16 %0, %1, %2" : "=v"(s) : "v"(ua), "v"(va));
    asm("v_pk_max_f16 %0, %1, 0" : "=v"(r) : "v"(s));
    return r;
}

// ---------------------------------------------------------------------------
// pre1 (+ fused prep + label histogram): blocks < mainBlocks do
//   u = [x|pos] @ (W1a - W1b) + b1 ; v = [x|pos] @ W1b   (D = 19)
// blocks >= mainBlocks: weight split hi/lo + qcnt label histogram.
// (qsums/qcnt zeroed by hipMemsetAsync BEFORE this kernel.)
// ---------------------------------------------------------------------------
__global__ void pre1_kernel(
    const float* __restrict__ x, const float* __restrict__ pos,
    const float* __restrict__ W1, const float* __restrict__ b1,
    unsigned short* __restrict__ U, unsigned short* __restrict__ V, int N,
    int mainBlocks,
    const float* __restrict__ W2a, const float* __restrict__ W2b,
    const float* __restrict__ W1c,
    unsigned short* __restrict__ hiA, unsigned short* __restrict__ loA,
    unsigned short* __restrict__ hiB, unsigned short* __restrict__ loB,
    unsigned short* __restrict__ wph, unsigned short* __restrict__ wpl,
    const int* __restrict__ labels, int* __restrict__ qcnt)
{
    if ((int)blockIdx.x >= mainBlocks) {
        int idx = (blockIdx.x - mainBlocks) * 256 + threadIdx.x;
        if (idx < 4096) {
            int j = idx >> 6, c = idx & 63;
            float w = W2a[idx];
            unsigned short h = f16r(w);
            unsigned short l = f16r(w - hs2f(h));
            hiA[c * 64 + j] = h; loA[c * 64 + j] = l;
            w = W2b[idx];
            h = f16r(w);
            l = f16r(w - hs2f(h));
            hiB[c * 64 + j] = h; loB[c * 64 + j] = l;
        }
        if (idx < 8192) {
            int d = idx & 63, cp = idx >> 6;
            float w = (cp < 64) ? (W1c[d * 64 + cp] - W1c[(d + 64) * 64 + cp])
                                : W1c[(d + 64) * 64 + (cp - 64)];
            unsigned short h = f16r(w);
            unsigned short l = f16r(w - hs2f(h));
            wph[cp * 64 + d] = h;
            wpl[cp * 64 + d] = l;
        }
        // label histogram -> qcnt (8192 threads grid-stride over N)
        {
            __shared__ int lh[8];
            int loc[8] = {0, 0, 0, 0, 0, 0, 0, 0};
            for (int n = idx; n < N; n += 8192) {
                int l = labels[n];
#pragma unroll
                for (int r = 0; r < 8; ++r) loc[r] += (l == r) ? 1 : 0;
            }
            if (threadIdx.x < 8) lh[threadIdx.x] = 0;
            __syncthreads();
#pragma unroll
            for (int r = 0; r < 8; ++r) if (loc[r]) atomicAdd(&lh[r], loc[r]);
            __syncthreads();
            if (threadIdx.x < 8) atomicAdd(&qcnt[threadIdx.x], lh[threadIdx.x]);
        }
        return;
    }

    int lane = threadIdx.x & 63;
    int gw   = (blockIdx.x * blockDim.x + threadIdx.x) >> 6;
    int tw   = (mainBlocks * blockDim.x) >> 6;

    float wd[19], wb[19];
#pragma unroll
    for (int d = 0; d < 19; ++d) {
        float a = W1[d * HDIM + lane];
        float b = W1[(d + 19) * HDIM + lane];
        wd[d] = a - b;
        wb[d] = b;
    }
    float bb = b1[lane];

    for (int n = gw; n < N; n += tw) {
        float su = 0.f, sv = 0.f;
#pragma unroll
        for (int d4 = 0; d4 < 4; ++d4) {
            fv4 h4 = *(const fv4*)&x[(size_t)n * 16 + 4 * d4];
#pragma unroll
            for (int k = 0; k < 4; ++k) {
                su += h4[k] * wd[4 * d4 + k];
                sv += h4[k] * wb[4 * d4 + k];
            }
        }
#pragma unroll
        for (int d = 0; d < 3; ++d) {
            float h = pos[(size_t)n * 3 + d];
            su += h * wd[16 + d];
            sv += h * wb[16 + d];
        }
        U[(size_t)n * HDIM + lane] = f16r(su + bb);
        V[(size_t)n * HDIM + lane] = f16r(sv);
    }
}

// ---------------------------------------------------------------------------
// pre_mfma (conv2 layer-1): [N x 64] @ [64 x 128] on MFMA (fp16).
// OPERAND-SWAPPED: mfma(W, h) so D row = channel, D col = node. Per lane the
// 4 acc elements of one nt are 4 CONSECUTIVE channels of node (base+m)
// -> 8 x 8B stores per tile instead of 32 x 2B.
// ---------------------------------------------------------------------------
__global__ __launch_bounds__(256, 2) void pre_mfma_kernel(
    const unsigned short* __restrict__ h,     // fp16 N x 64
    const unsigned short* __restrict__ Whi,   // fp16 [c' 0..127][d 0..63]
    const unsigned short* __restrict__ Wlo,
    const float* __restrict__ b1,
    unsigned short* __restrict__ U, unsigned short* __restrict__ V, int nTiles)
{
    int lane = threadIdx.x & 63;
    int quad = lane >> 4;
    int m    = lane & 15;
    int gw   = (blockIdx.x * blockDim.x + threadIdx.x) >> 6;
    int tw   = (gridDim.x * blockDim.x) >> 6;

    hf8 Bh[8][2], Bl[8][2];
#pragma unroll
    for (int nt = 0; nt < 8; ++nt)
#pragma unroll
        for (int ks = 0; ks < 2; ++ks) {
            int off = (nt * 16 + m) * 64 + ks * 32 + quad * 8;
            Bh[nt][ks] = *(const hf8*)&Whi[off];
            Bl[nt][ks] = *(const hf8*)&Wlo[off];
        }
    float bias[16];        // [nt][r] = b1[nt*16 + quad*4 + r]
#pragma unroll
    for (int nt = 0; nt < 4; ++nt)
#pragma unroll
        for (int r = 0; r < 4; ++r)
            bias[nt * 4 + r] = b1[nt * 16 + quad * 4 + r];

    for (int t = gw; t < nTiles; t += tw) {
        int base = t * 16;
        hf8 A[2];
#pragma unroll
        for (int ks = 0; ks < 2; ++ks)
            A[ks] = *(const hf8*)&h[(size_t)(base + m) * HDIM + ks * 32 + quad * 8];

        f32x4 acc[8] = {{0,0,0,0},{0,0,0,0},{0,0,0,0},{0,0,0,0},
                        {0,0,0,0},{0,0,0,0},{0,0,0,0},{0,0,0,0}};
#pragma unroll
        for (int ks = 0; ks < 2; ++ks)
#pragma unroll
            for (int nt = 0; nt < 8; ++nt) {
                acc[nt] = __builtin_amdgcn_mfma_f32_16x16x32_f16(Bl[nt][ks], A[ks], acc[nt], 0, 0, 0);
                acc[nt] = __builtin_amdgcn_mfma_f32_16x16x32_f16(Bh[nt][ks], A[ks], acc[nt], 0, 0, 0);
            }

        // lane (quad,m): acc[nt][r] = out[node=base+m][channel nt*16+quad*4+r]
#pragma unroll
        for (int nt = 0; nt < 8; ++nt) {
            unsigned short* __restrict__ dst = (nt < 4) ? U : V;
            int c0 = (nt & 3) * 16 + quad * 4;
            float a0 = acc[nt][0] + ((nt < 4) ? bias[nt * 4 + 0] : 0.f);
            float a1 = acc[nt][1] + ((nt < 4) ? bias[nt * 4 + 1] : 0.f);
            float a2 = acc[nt][2] + ((nt < 4) ? bias[nt * 4 + 2] : 0.f);
            float a3 = acc[nt][3] + ((nt < 4) ? bias[nt * 4 + 3] : 0.f);
            u32x2 pk;
            pk[0] = (unsigned)f16r(a0) | ((unsigned)f16r(a1) << 16);
            pk[1] = (unsigned)f16r(a2) | ((unsigned)f16r(a3) << 16);
            *(u32x2*)&dst[(size_t)(base + m) * HDIM + c0] = pk;
        }
    }
}

// ---------------------------------------------------------------------------
// edge_mfma<POOL>: out[t][c] = relu( max_{16 edges}( relu(u[t]+v[src]) @ W2 )[c] + b2[c] )
// ROUND-6 VERIFIED STRUCTURE: 32 nodes/block (3125 blocks), depth-2 with
// exactly TWO static buffer sets (A,B) -> VGPR ~76-84, NO spill. (Round 7's
// 4-set pipeline let the scheduler hoist all issues together: 128 live VGPRs,
// 24B/thread scratch, vmcnt queue poisoned -> 2x regression.)
// W2 hi/lo in swizzled LDS; block's 32 U rows in LDS.
// POOL=1 (conv2): skip h2 store; accumulate per-region channel sums in 8
// VGPRs -> LDS reduce -> global atomics (region_mean fused away).
// ---------------------------------------------------------------------------
#define FOLD_HALF(V0, V1, OFF)                                                     \
    _Pragma("unroll")                                                              \
    for (int mt = 0; mt < 4; ++mt) {                                               \
        int urow = wave * 8 + (OFF) + mt;                                          \
        u32x4 u0 = *(const u32x4*)((const char*)Ush + urow * 128 + quad * 16);     \
        u32x4 u1 = *(const u32x4*)((const char*)Ush + urow * 128 + 64 + quad * 16);\
        u32x4 a0, a1;                                                              \
        _Pragma("unroll")                                                          \
        for (int p = 0; p < 4; ++p) {                                              \
            a0[p] = addrelu2(u0[p], V0[mt][p]);                                    \
            a1[p] = addrelu2(u1[p], V1[mt][p]);                                    \
        }                                                                          \
        hf8 A0 = __builtin_bit_cast(hf8, a0);                                      \
        hf8 A1 = __builtin_bit_cast(hf8, a1);                                      \
        f32x4 acc[4] = {{0,0,0,0},{0,0,0,0},{0,0,0,0},{0,0,0,0}};                  \
        _Pragma("unroll")                                                          \
        for (int nt = 0; nt < 4; ++nt) {                                           \
            int bb  = nt * 2048 + m * 128 + quad * 16;                             \
            int bs0 = bb ^ ((m & 7) << 4);                                         \
            int bs1 = (bb + 64) ^ ((m & 7) << 4);                                  \
            hf8 Bh0 = *(const hf8*)((const char*)Wsh + bs0);                       \
            hf8 Bl0 = *(const hf8*)((const char*)Wsh + 8192 + bs0);                \
            hf8 Bh1 = *(const hf8*)((const char*)Wsh + bs1);                       \
            hf8 Bl1 = *(const hf8*)((const char*)Wsh + 8192 + bs1);                \
            acc[nt] = __builtin_amdgcn_mfma_f32_16x16x32_f16(A0, Bl0, acc[nt], 0, 0, 0); \
            acc[nt] = __builtin_amdgcn_mfma_f32_16x16x32_f16(A0, Bh0, acc[nt], 0, 0, 0); \
            acc[nt] = __builtin_amdgcn_mfma_f32_16x16x32_f16(A1, Bl1, acc[nt], 0, 0, 0); \
            acc[nt] = __builtin_amdgcn_mfma_f32_16x16x32_f16(A1, Bh1, acc[nt], 0, 0, 0); \
        }                                                                          \
        float mx[4];                                                               \
        _Pragma("unroll")                                                          \
        for (int nt = 0; nt < 4; ++nt)                                             \
            mx[nt] = fmaxf(fmaxf(acc[nt][0], acc[nt][1]), fmaxf(acc[nt][2], acc[nt][3])); \
        _Pragma("unroll")                                                          \
        for (int nt = 0; nt < 4; ++nt) {                                           \
            mx[nt] = fmaxf(mx[nt], __shfl_xor(mx[nt], 16));                        \
            mx[nt] = fmaxf(mx[nt], __shfl_xor(mx[nt], 32));                        \
        }                                                                          \
        float val = (quad == 0) ? mx[0] : (quad == 1) ? mx[1] : (quad == 2) ? mx[2] : mx[3]; \
        float hv = fmaxf(val + b2v, 0.f);                                          \
        if constexpr (POOL) {                                                      \
            int lbl = labels[nb + (OFF) + mt];                                     \
            _Pragma("unroll")                                                      \
            for (int r = 0; r < 8; ++r) pacc[r] += (lbl == r) ? hv : 0.f;          \
        } else {                                                                   \
            out[(size_t)(nb + (OFF) + mt) * HDIM + lane] = f16r(hv);               \
        }                                                                          \
    }

template<int POOL>
__global__ __launch_bounds__(256, 3) void edge_mfma_kernel(
    const unsigned short* __restrict__ U, const unsigned short* __restrict__ V,
    const int* __restrict__ src,
    const unsigned short* __restrict__ Whi, const unsigned short* __restrict__ Wlo,
    const float* __restrict__ b2, unsigned short* __restrict__ out,
    const int* __restrict__ labels, float* __restrict__ qsums)
{
    __shared__ __align__(16) unsigned short Wsh[8192];   // 16 KB: hi @0, lo @8192B
    __shared__ __align__(16) unsigned short Ush[2048];   // 4 KB: 32 U rows

    int tid  = threadIdx.x;
    int wave = tid >> 6;
    int lane = tid & 63;
    int quad = lane >> 4;
    int m    = lane & 15;

    int nbB = blockIdx.x * 32;           // block node base
    int nb  = nbB + wave * 8;            // wave's 8 nodes

    // ---- stage W2 hi/lo into LDS with row-XOR swizzle ------------------
#pragma unroll
    for (int it = 0; it < 4; ++it) {
        int chunk = it * 256 + tid;
        int reg   = it >> 1;                  // it 0,1 -> hi ; 2,3 -> lo
        int b     = (chunk & 511) * 16;
        int bs    = b ^ (((b >> 7) & 7) << 4);
        const unsigned short* sp = reg ? Wlo : Whi;
        u32x4 d = *(const u32x4*)((const char*)sp + b);
        *(u32x4*)((char*)Wsh + reg * 8192 + bs) = d;
    }
    // ---- stage block's 32 U rows (contiguous 4 KB) ---------------------
    *(u32x4*)((char*)Ush + tid * 16) =
        *(const u32x4*)((const char*)(U + (size_t)nbB * HDIM) + tid * 16);

    int  srcA = src[(size_t)nb * 16 + lane];
    int  srcB = src[(size_t)(nb + 4) * 16 + lane];
    float b2v = b2[lane];
    float pacc[8] = {0, 0, 0, 0, 0, 0, 0, 0};

    __syncthreads();     // drains everything; placed BEFORE gather issue

    // ---- issue all V gathers: tile A first (older), then tile B --------
    u32x4 vA0[4], vA1[4], vB0[4], vB1[4];
#pragma unroll
    for (int mt = 0; mt < 4; ++mt) {
        int s_ = __shfl(srcA, mt * 16 + m);
        const u32x4* vp = (const u32x4*)(V + (size_t)s_ * HDIM + quad * 8);
        vA0[mt] = vp[0]; vA1[mt] = vp[4];
    }
#pragma unroll
    for (int mt = 0; mt < 4; ++mt) {
        int s_ = __shfl(srcB, mt * 16 + m);
        const u32x4* vp = (const u32x4*)(V + (size_t)s_ * HDIM + quad * 8);
        vB0[mt] = vp[0]; vB1[mt] = vp[4];
    }

    // ---- tile A (B's 8 gathers remain in flight), then tile B ----------
    FOLD_HALF(vA0, vA1, 0)
    FOLD_HALF(vB0, vB1, 4)

    if constexpr (POOL) {
        float* ls = (float*)Ush;            // reuse U staging (4KB >= 512 f32)
        __syncthreads();                    // all waves done reading Ush
        for (int idx = tid; idx < 512; idx += 256) ls[idx] = 0.f;
        __syncthreads();
#pragma unroll
        for (int r = 0; r < 8; ++r) atomicAdd(&ls[r * 64 + lane], pacc[r]);
        __syncthreads();
        for (int idx = tid; idx < 512; idx += 256) atomicAdd(&qsums[idx], ls[idx]);
    }
}

// ---------------------------------------------------------------------------
// tail: fully parallel quotient convs (8 nodes, 32 edges) + pool + linear.
// ---------------------------------------------------------------------------
#define EQ_MAX 64
__global__ void tail_kernel(const float* __restrict__ qsums, const int* __restrict__ qcnt,
                            const int* __restrict__ qei, int Eq,
                            const float* __restrict__ W31, const float* __restrict__ b31,
                            const float* __restrict__ W32, const float* __restrict__ b32,
                            const float* __restrict__ W41, const float* __restrict__ b41,
                            const float* __restrict__ W42, const float* __restrict__ b42,
                            const float* __restrict__ linW, const float* __restrict__ linb,
                            float* __restrict__ out)
{
    __shared__ float qx[512], uu[512], vv[512];
    __shared__ float hr[EQ_MAX * 64], me[EQ_MAX * 64];
    __shared__ __align__(16) float W2s[64 * 64];
    __shared__ int   qes[EQ_MAX], qet[EQ_MAX];
    __shared__ float emb[64];

    int tid = threadIdx.x;
    if (Eq > EQ_MAX) Eq = EQ_MAX;

    if (tid < Eq) { qes[tid] = qei[tid]; qet[tid] = qei[Eq + tid]; }
    for (int idx = tid; idx < 512; idx += 256) {
        int r = idx >> 6;
        int cc = qcnt[r];
        qx[idx] = (cc > 0) ? qsums[idx] / (float)cc : 0.f;
    }
    __syncthreads();

    for (int layer = 0; layer < 2; ++layer) {
        const float* W1p = layer ? W41 : W31;
        const float* b1p = layer ? b41 : b31;
        const float* W2p = layer ? W42 : W32;
        const float* b2p = layer ? b42 : b32;

        for (int idx = tid * 4; idx < 4096; idx += 1024)
            *(fv4*)&W2s[idx] = *(const fv4*)&W2p[idx];

        for (int idx = tid; idx < 512; idx += 256) {
            int t = idx >> 6, c = idx & 63;
            float su = 0.f, sv = 0.f;
#pragma unroll 8
            for (int d = 0; d < 64; ++d) {
                float hv = qx[t * 64 + d];
                float a = W1p[d * 64 + c];
                float b = W1p[(d + 64) * 64 + c];
                su += hv * (a - b);
                sv += hv * b;
            }
            uu[idx] = su + b1p[c];
            vv[idx] = sv;
        }
        __syncthreads();

        for (int idx = tid; idx < Eq * 64; idx += 256) {
            int e = idx >> 6, c = idx & 63;
            hr[idx] = fmaxf(uu[qet[e] * 64 + c] + vv[qes[e] * 64 + c], 0.f);
        }
        __syncthreads();

        {
            int c = tid & 63, e0 = tid >> 6;
            for (int e = e0; e < Eq; e += 4) {
                float acc = 0.f;
#pragma unroll 8
                for (int j = 0; j < 64; ++j)
                    acc += hr[e * 64 + j] * W2s[j * 64 + c];
                me[e * 64 + c] = acc;
            }
        }
        __syncthreads();

        for (int idx = tid; idx < 512; idx += 256) {
            int t = idx >> 6, c = idx & 63;
            float a = -INFINITY;
            for (int e = 0; e < Eq; ++e)
                if (qet[e] == t) a = fmaxf(a, me[e * 64 + c]);
            float vout = (a == -INFINITY) ? 0.f : (a + b2p[c]);
            qx[idx] = fmaxf(vout, 0.f);
        }
        __syncthreads();
    }

    if (tid < 64) {
        float s = 0.f;
        for (int r = 0; r < 8; ++r) s += qx[r * 64 + tid];
        emb[tid] = s;
    }
    __syncthreads();
    if (tid < 8) {
        float o = linb[tid];
        for (int c = 0; c < 64; ++c) o += emb[c] * linW[c * 8 + tid];
        out[tid] = o;
    }
}

// ---------------------------------------------------------------------------
extern "C" void kernel_launch(void* const* d_in, const int* in_sizes, int n_in,
                              void* d_out, int out_size, void* d_ws, size_t ws_size,
                              hipStream_t stream)
{
    const float* x    = (const float*)d_in[0];
    const float* pos  = (const float*)d_in[1];
    const int*   ei   = (const int*)d_in[2];
    const int*   lbl  = (const int*)d_in[3];
    const int*   qei  = (const int*)d_in[4];
    const float* W11 = (const float*)d_in[5];
    const float* b11 = (const float*)d_in[6];
    const float* W12 = (const float*)d_in[7];
    const float* b12 = (const float*)d_in[8];
    const float* W21 = (const float*)d_in[9];
    const float* b21 = (const float*)d_in[10];
    const float* W22 = (const float*)d_in[11];
    const float* b22 = (const float*)d_in[12];
    const float* W31 = (const float*)d_in[13];
    const float* b31 = (const float*)d_in[14];
    const float* W32 = (const float*)d_in[15];
    const float* b32 = (const float*)d_in[16];
    const float* W41 = (const float*)d_in[17];
    const float* b41 = (const float*)d_in[18];
    const float* W42 = (const float*)d_in[19];
    const float* b42 = (const float*)d_in[20];
    const float* linW = (const float*)d_in[21];
    const float* linb = (const float*)d_in[22];

    int N  = in_sizes[0] / 16;          // 100000
    int Eq = in_sizes[4] / 2;           // 32
    const int* src = ei;                // row 0 = src; tgt = repeat(arange(N),16)

    size_t NH = (size_t)N * HDIM;
    unsigned short* hbf = (unsigned short*)d_ws;   // fp16 N*64 (h1)
    unsigned short* Ub  = hbf + NH;                // fp16 N*64
    unsigned short* Vb  = Ub + NH;                 // fp16 N*64
    unsigned short* w2h1 = Vb + NH;
    unsigned short* w2l1 = w2h1 + 4096;
    unsigned short* w2h2 = w2l1 + 4096;
    unsigned short* w2l2 = w2h2 + 4096;
    unsigned short* wph  = w2l2 + 4096;            // 8192
    unsigned short* wpl  = wph + 8192;             // 8192
    float* qsums = (float*)(wpl + 8192);
    int*   qcnt  = (int*)(qsums + 512);

    (void)hipMemsetAsync(qsums, 0, 512 * sizeof(float) + 8 * sizeof(int), stream);

    int nTiles      = N / 16;           // pre_mfma tiles (6250)
    int edgeBlocks  = N / 32;           // edge blocks, 32 nodes each (3125)
    int mainBlocks  = 2048;

    // conv1 (pre1 + fused prep + label histogram)
    pre1_kernel<<<mainBlocks + 32, 256, 0, stream>>>(
        x, pos, W11, b11, Ub, Vb, N, mainBlocks,
        W12, W22, W21, w2h1, w2l1, w2h2, w2l2, wph, wpl, lbl, qcnt);
    edge_mfma_kernel<0><<<edgeBlocks, 256, 0, stream>>>(
        Ub, Vb, src, w2h1, w2l1, b12, hbf, lbl, qsums);
    // conv2
    pre_mfma_kernel<<<1563, 256, 0, stream>>>(hbf, wph, wpl, b21, Ub, Vb, nTiles);
    // conv2 edge + fused region-sum pooling (h2 never materialized)
    edge_mfma_kernel<1><<<edgeBlocks, 256, 0, stream>>>(
        Ub, Vb, src, w2h2, w2l2, b22, hbf, lbl, qsums);
    // quotient tail
    tail_kernel<<<1, 256, 0, stream>>>(qsums, qcnt, qei, Eq,
                                       W31, b31, W32, b32,
                                       W41, b41, W42, b42,
                                       linW, linb, (float*)d_out);
}

// Round 9
// 317.340 us; speedup vs baseline: 1.0942x; 1.0942x over previous
//
#include <hip/hip_runtime.h>
#include <hip/hip_fp16.h>

typedef float fv4 __attribute__((ext_vector_type(4)));
using hf8   = __attribute__((ext_vector_type(8))) _Float16;  // 8 fp16 = 4 VGPRs (MFMA A/B frag)
using f32x4 = __attribute__((ext_vector_type(4))) float;     // MFMA C/D frag
using u32x4 = __attribute__((ext_vector_type(4))) unsigned;
using u32x2 = __attribute__((ext_vector_type(2))) unsigned;

#define HDIM 64

// fp32 -> fp16 bits (RNE)
__device__ __forceinline__ unsigned short f16r(float f) {
    return __half_as_ushort(__float2half(f));
}
__device__ __forceinline__ float hs2f(unsigned short s) {
    return __half2float(__ushort_as_half(s));
}
// packed fp16: relu(u+v) on 2 channels in one reg (v_pk_add_f16 + v_pk_max_f16)
__device__ __forceinline__ unsigned addrelu2(unsigned ua, unsigned va) {
    unsigned s, r;
    asm("v_pk_add_f16 %0, %1, %2" : "=v"(s) : "v"(ua), "v"(va));
    asm("v_pk_max_f16 %0, %1, 0" : "=v"(r) : "v"(s));
    return r;
}

// ---------------------------------------------------------------------------
// pre1 (+ fused prep + label histogram): blocks < mainBlocks do
//   u = [x|pos] @ (W1a - W1b) + b1 ; v = [x|pos] @ W1b   (D = 19)
// blocks >= mainBlocks: weight split hi/lo + qcnt label histogram.
// (qsums/qcnt zeroed by hipMemsetAsync BEFORE this kernel.)
// ---------------------------------------------------------------------------
__global__ void pre1_kernel(
    const float* __restrict__ x, const float* __restrict__ pos,
    const float* __restrict__ W1, const float* __restrict__ b1,
    unsigned short* __restrict__ U, unsigned short* __restrict__ V, int N,
    int mainBlocks,
    const float* __restrict__ W2a, const float* __restrict__ W2b,
    const float* __restrict__ W1c,
    unsigned short* __restrict__ hiA, unsigned short* __restrict__ loA,
    unsigned short* __restrict__ hiB, unsigned short* __restrict__ loB,
    unsigned short* __restrict__ wph, unsigned short* __restrict__ wpl,
    const int* __restrict__ labels, int* __restrict__ qcnt)
{
    if ((int)blockIdx.x >= mainBlocks) {
        int idx = (blockIdx.x - mainBlocks) * 256 + threadIdx.x;
        if (idx < 4096) {
            int j = idx >> 6, c = idx & 63;
            float w = W2a[idx];
            unsigned short h = f16r(w);
            unsigned short l = f16r(w - hs2f(h));
            hiA[c * 64 + j] = h; loA[c * 64 + j] = l;
            w = W2b[idx];
            h = f16r(w);
            l = f16r(w - hs2f(h));
            hiB[c * 64 + j] = h; loB[c * 64 + j] = l;
        }
        if (idx < 8192) {
            int d = idx & 63, cp = idx >> 6;
            float w = (cp < 64) ? (W1c[d * 64 + cp] - W1c[(d + 64) * 64 + cp])
                                : W1c[(d + 64) * 64 + (cp - 64)];
            unsigned short h = f16r(w);
            unsigned short l = f16r(w - hs2f(h));
            wph[cp * 64 + d] = h;
            wpl[cp * 64 + d] = l;
        }
        // label histogram -> qcnt (8192 threads grid-stride over N)
        {
            __shared__ int lh[8];
            int loc[8] = {0, 0, 0, 0, 0, 0, 0, 0};
            for (int n = idx; n < N; n += 8192) {
                int l = labels[n];
#pragma unroll
                for (int r = 0; r < 8; ++r) loc[r] += (l == r) ? 1 : 0;
            }
            if (threadIdx.x < 8) lh[threadIdx.x] = 0;
            __syncthreads();
#pragma unroll
            for (int r = 0; r < 8; ++r) if (loc[r]) atomicAdd(&lh[r], loc[r]);
            __syncthreads();
            if (threadIdx.x < 8) atomicAdd(&qcnt[threadIdx.x], lh[threadIdx.x]);
        }
        return;
    }

    int lane = threadIdx.x & 63;
    int gw   = (blockIdx.x * blockDim.x + threadIdx.x) >> 6;
    int tw   = (mainBlocks * blockDim.x) >> 6;

    float wd[19], wb[19];
#pragma unroll
    for (int d = 0; d < 19; ++d) {
        float a = W1[d * HDIM + lane];
        float b = W1[(d + 19) * HDIM + lane];
        wd[d] = a - b;
        wb[d] = b;
    }
    float bb = b1[lane];

    for (int n = gw; n < N; n += tw) {
        float su = 0.f, sv = 0.f;
#pragma unroll
        for (int d4 = 0; d4 < 4; ++d4) {
            fv4 h4 = *(const fv4*)&x[(size_t)n * 16 + 4 * d4];
#pragma unroll
            for (int k = 0; k < 4; ++k) {
                su += h4[k] * wd[4 * d4 + k];
                sv += h4[k] * wb[4 * d4 + k];
            }
        }
#pragma unroll
        for (int d = 0; d < 3; ++d) {
            float h = pos[(size_t)n * 3 + d];
            su += h * wd[16 + d];
            sv += h * wb[16 + d];
        }
        U[(size_t)n * HDIM + lane] = f16r(su + bb);
        V[(size_t)n * HDIM + lane] = f16r(sv);
    }
}

// ---------------------------------------------------------------------------
// pre_mfma (conv2 layer-1): [N x 64] @ [64 x 128] on MFMA (fp16).
// OPERAND-SWAPPED: mfma(W, h) so D row = channel, D col = node. Per lane the
// 4 acc elements of one nt are 4 CONSECUTIVE channels of node (base+m)
// -> 8 x 8B stores per tile instead of 32 x 2B.
// ---------------------------------------------------------------------------
__global__ __launch_bounds__(256, 2) void pre_mfma_kernel(
    const unsigned short* __restrict__ h,     // fp16 N x 64
    const unsigned short* __restrict__ Whi,   // fp16 [c' 0..127][d 0..63]
    const unsigned short* __restrict__ Wlo,
    const float* __restrict__ b1,
    unsigned short* __restrict__ U, unsigned short* __restrict__ V, int nTiles)
{
    int lane = threadIdx.x & 63;
    int quad = lane >> 4;
    int m    = lane & 15;
    int gw   = (blockIdx.x * blockDim.x + threadIdx.x) >> 6;
    int tw   = (gridDim.x * blockDim.x) >> 6;

    hf8 Bh[8][2], Bl[8][2];
#pragma unroll
    for (int nt = 0; nt < 8; ++nt)
#pragma unroll
        for (int ks = 0; ks < 2; ++ks) {
            int off = (nt * 16 + m) * 64 + ks * 32 + quad * 8;
            Bh[nt][ks] = *(const hf8*)&Whi[off];
            Bl[nt][ks] = *(const hf8*)&Wlo[off];
        }
    float bias[16];        // [nt][r] = b1[nt*16 + quad*4 + r]
#pragma unroll
    for (int nt = 0; nt < 4; ++nt)
#pragma unroll
        for (int r = 0; r < 4; ++r)
            bias[nt * 4 + r] = b1[nt * 16 + quad * 4 + r];

    for (int t = gw; t < nTiles; t += tw) {
        int base = t * 16;
        hf8 A[2];
#pragma unroll
        for (int ks = 0; ks < 2; ++ks)
            A[ks] = *(const hf8*)&h[(size_t)(base + m) * HDIM + ks * 32 + quad * 8];

        f32x4 acc[8] = {{0,0,0,0},{0,0,0,0},{0,0,0,0},{0,0,0,0},
                        {0,0,0,0},{0,0,0,0},{0,0,0,0},{0,0,0,0}};
#pragma unroll
        for (int ks = 0; ks < 2; ++ks)
#pragma unroll
            for (int nt = 0; nt < 8; ++nt) {
                acc[nt] = __builtin_amdgcn_mfma_f32_16x16x32_f16(Bl[nt][ks], A[ks], acc[nt], 0, 0, 0);
                acc[nt] = __builtin_amdgcn_mfma_f32_16x16x32_f16(Bh[nt][ks], A[ks], acc[nt], 0, 0, 0);
            }

        // lane (quad,m): acc[nt][r] = out[node=base+m][channel nt*16+quad*4+r]
#pragma unroll
        for (int nt = 0; nt < 8; ++nt) {
            unsigned short* __restrict__ dst = (nt < 4) ? U : V;
            int c0 = (nt & 3) * 16 + quad * 4;
            float a0 = acc[nt][0] + ((nt < 4) ? bias[nt * 4 + 0] : 0.f);
            float a1 = acc[nt][1] + ((nt < 4) ? bias[nt * 4 + 1] : 0.f);
            float a2 = acc[nt][2] + ((nt < 4) ? bias[nt * 4 + 2] : 0.f);
            float a3 = acc[nt][3] + ((nt < 4) ? bias[nt * 4 + 3] : 0.f);
            u32x2 pk;
            pk[0] = (unsigned)f16r(a0) | ((unsigned)f16r(a1) << 16);
            pk[1] = (unsigned)f16r(a2) | ((unsigned)f16r(a3) << 16);
            *(u32x2*)&dst[(size_t)(base + m) * HDIM + c0] = pk;
        }
    }
}

// ---------------------------------------------------------------------------
// edge_mfma<POOL>: round-6 verified structure (32 nodes/block, depth-2, two
// static buffer sets, VGPR ~76, no spill). POOL=1 fixes round 8's regression:
// label loads are HOISTED before the barrier (one VMEM load, lane<8) and
// folds get their label via __shfl -- NO memory op inside the fold phase, so
// the in-order vmem queue never drains tile-B's prefetch early. Global
// atomics banked 8x to cut same-word contention.
// ---------------------------------------------------------------------------
#define FOLD_HALF(V0, V1, OFF)                                                     \
    _Pragma("unroll")                                                              \
    for (int mt = 0; mt < 4; ++mt) {                                               \
        int urow = wave * 8 + (OFF) + mt;                                          \
        u32x4 u0 = *(const u32x4*)((const char*)Ush + urow * 128 + quad * 16);     \
        u32x4 u1 = *(const u32x4*)((const char*)Ush + urow * 128 + 64 + quad * 16);\
        u32x4 a0, a1;                                                              \
        _Pragma("unroll")                                                          \
        for (int p = 0; p < 4; ++p) {                                              \
            a0[p] = addrelu2(u0[p], V0[mt][p]);                                    \
            a1[p] = addrelu2(u1[p], V1[mt][p]);                                    \
        }                                                                          \
        hf8 A0 = __builtin_bit_cast(hf8, a0);                                      \
        hf8 A1 = __builtin_bit_cast(hf8, a1);                                      \
        f32x4 acc[4] = {{0,0,0,0},{0,0,0,0},{0,0,0,0},{0,0,0,0}};                  \
        _Pragma("unroll")                                                          \
        for (int nt = 0; nt < 4; ++nt) {                                           \
            int bb  = nt * 2048 + m * 128 + quad * 16;                             \
            int bs0 = bb ^ ((m & 7) << 4);                                         \
            int bs1 = (bb + 64) ^ ((m & 7) << 4);                                  \
            hf8 Bh0 = *(const hf8*)((const char*)Wsh + bs0);                       \
            hf8 Bl0 = *(const hf8*)((const char*)Wsh + 8192 + bs0);                \
            hf8 Bh1 = *(const hf8*)((const char*)Wsh + bs1);                       \
            hf8 Bl1 = *(const hf8*)((const char*)Wsh + 8192 + bs1);                \
            acc[nt] = __builtin_amdgcn_mfma_f32_16x16x32_f16(A0, Bl0, acc[nt], 0, 0, 0); \
            acc[nt] = __builtin_amdgcn_mfma_f32_16x16x32_f16(A0, Bh0, acc[nt], 0, 0, 0); \
            acc[nt] = __builtin_amdgcn_mfma_f32_16x16x32_f16(A1, Bl1, acc[nt], 0, 0, 0); \
            acc[nt] = __builtin_amdgcn_mfma_f32_16x16x32_f16(A1, Bh1, acc[nt], 0, 0, 0); \
        }                                                                          \
        float mx[4];                                                               \
        _Pragma("unroll")                                                          \
        for (int nt = 0; nt < 4; ++nt)                                             \
            mx[nt] = fmaxf(fmaxf(acc[nt][0], acc[nt][1]), fmaxf(acc[nt][2], acc[nt][3])); \
        _Pragma("unroll")                                                          \
        for (int nt = 0; nt < 4; ++nt) {                                           \
            mx[nt] = fmaxf(mx[nt], __shfl_xor(mx[nt], 16));                        \
            mx[nt] = fmaxf(mx[nt], __shfl_xor(mx[nt], 32));                        \
        }                                                                          \
        float val = (quad == 0) ? mx[0] : (quad == 1) ? mx[1] : (quad == 2) ? mx[2] : mx[3]; \
        float hv = fmaxf(val + b2v, 0.f);                                          \
        if constexpr (POOL) {                                                      \
            int lbl = __shfl(labv, (OFF) + mt);                                    \
            _Pragma("unroll")                                                      \
            for (int r = 0; r < 8; ++r) pacc[r] += (lbl == r) ? hv : 0.f;          \
        } else {                                                                   \
            out[(size_t)(nb + (OFF) + mt) * HDIM + lane] = f16r(hv);               \
        }                                                                          \
    }

template<int POOL>
__global__ __launch_bounds__(256, 3) void edge_mfma_kernel(
    const unsigned short* __restrict__ U, const unsigned short* __restrict__ V,
    const int* __restrict__ src,
    const unsigned short* __restrict__ Whi, const unsigned short* __restrict__ Wlo,
    const float* __restrict__ b2, unsigned short* __restrict__ out,
    const int* __restrict__ labels, float* __restrict__ qsums)
{
    __shared__ __align__(16) unsigned short Wsh[8192];   // 16 KB: hi @0, lo @8192B
    __shared__ __align__(16) unsigned short Ush[2048];   // 4 KB: 32 U rows

    int tid  = threadIdx.x;
    int wave = tid >> 6;
    int lane = tid & 63;
    int quad = lane >> 4;
    int m    = lane & 15;

    int nbB = blockIdx.x * 32;           // block node base
    int nb  = nbB + wave * 8;            // wave's 8 nodes

    // ---- stage W2 hi/lo into LDS with row-XOR swizzle ------------------
#pragma unroll
    for (int it = 0; it < 4; ++it) {
        int chunk = it * 256 + tid;
        int reg   = it >> 1;                  // it 0,1 -> hi ; 2,3 -> lo
        int b     = (chunk & 511) * 16;
        int bs    = b ^ (((b >> 7) & 7) << 4);
        const unsigned short* sp = reg ? Wlo : Whi;
        u32x4 d = *(const u32x4*)((const char*)sp + b);
        *(u32x4*)((char*)Wsh + reg * 8192 + bs) = d;
    }
    // ---- stage block's 32 U rows (contiguous 4 KB) ---------------------
    *(u32x4*)((char*)Ush + tid * 16) =
        *(const u32x4*)((const char*)(U + (size_t)nbB * HDIM) + tid * 16);

    int  srcA = src[(size_t)nb * 16 + lane];
    int  srcB = src[(size_t)(nb + 4) * 16 + lane];
    float b2v = b2[lane];
    float pacc[8] = {0, 0, 0, 0, 0, 0, 0, 0};
    int labv = 0;
    if (POOL && lane < 8) labv = labels[nb + lane];   // hoisted: NOT in fold

    __syncthreads();     // drains everything; placed BEFORE gather issue

    // ---- issue all V gathers: tile A first (older), then tile B --------
    u32x4 vA0[4], vA1[4], vB0[4], vB1[4];
#pragma unroll
    for (int mt = 0; mt < 4; ++mt) {
        int s_ = __shfl(srcA, mt * 16 + m);
        const u32x4* vp = (const u32x4*)(V + (size_t)s_ * HDIM + quad * 8);
        vA0[mt] = vp[0]; vA1[mt] = vp[4];
    }
#pragma unroll
    for (int mt = 0; mt < 4; ++mt) {
        int s_ = __shfl(srcB, mt * 16 + m);
        const u32x4* vp = (const u32x4*)(V + (size_t)s_ * HDIM + quad * 8);
        vB0[mt] = vp[0]; vB1[mt] = vp[4];
    }

    // ---- tile A (B's 8 gathers remain in flight), then tile B ----------
    FOLD_HALF(vA0, vA1, 0)
    FOLD_HALF(vB0, vB1, 4)

    if constexpr (POOL) {
        float* ls = (float*)Ush;            // reuse U staging (4KB >= 512 f32)
        float* qs = qsums + (blockIdx.x & 7) * 512;   // 8-way banked atomics
        __syncthreads();                    // all waves done reading Ush
        for (int idx = tid; idx < 512; idx += 256) ls[idx] = 0.f;
        __syncthreads();
#pragma unroll
        for (int r = 0; r < 8; ++r) atomicAdd(&ls[r * 64 + lane], pacc[r]);
        __syncthreads();
        for (int idx = tid; idx < 512; idx += 256) atomicAdd(&qs[idx], ls[idx]);
    }
}

// ---------------------------------------------------------------------------
// tail: fully parallel quotient convs (8 nodes, 32 edges) + pool + linear.
// qsums is 8-way banked: sum banks while loading.
// ---------------------------------------------------------------------------
#define EQ_MAX 64
__global__ void tail_kernel(const float* __restrict__ qsums, const int* __restrict__ qcnt,
                            const int* __restrict__ qei, int Eq,
                            const float* __restrict__ W31, const float* __restrict__ b31,
                            const float* __restrict__ W32, const float* __restrict__ b32,
                            const float* __restrict__ W41, const float* __restrict__ b41,
                            const float* __restrict__ W42, const float* __restrict__ b42,
                            const float* __restrict__ linW, const float* __restrict__ linb,
                            float* __restrict__ out)
{
    __shared__ float qx[512], uu[512], vv[512];
    __shared__ float hr[EQ_MAX * 64], me[EQ_MAX * 64];
    __shared__ __align__(16) float W2s[64 * 64];
    __shared__ int   qes[EQ_MAX], qet[EQ_MAX];
    __shared__ float emb[64];

    int tid = threadIdx.x;
    if (Eq > EQ_MAX) Eq = EQ_MAX;

    if (tid < Eq) { qes[tid] = qei[tid]; qet[tid] = qei[Eq + tid]; }
    for (int idx = tid; idx < 512; idx += 256) {
        int r = idx >> 6;
        int cc = qcnt[r];
        float s = 0.f;
#pragma unroll
        for (int bk = 0; bk < 8; ++bk) s += qsums[bk * 512 + idx];
        qx[idx] = (cc > 0) ? s / (float)cc : 0.f;
    }
    __syncthreads();

    for (int layer = 0; layer < 2; ++layer) {
        const float* W1p = layer ? W41 : W31;
        const float* b1p = layer ? b41 : b31;
        const float* W2p = layer ? W42 : W32;
        const float* b2p = layer ? b42 : b32;

        for (int idx = tid * 4; idx < 4096; idx += 1024)
            *(fv4*)&W2s[idx] = *(const fv4*)&W2p[idx];

        for (int idx = tid; idx < 512; idx += 256) {
            int t = idx >> 6, c = idx & 63;
            float su = 0.f, sv = 0.f;
#pragma unroll 8
            for (int d = 0; d < 64; ++d) {
                float hv = qx[t * 64 + d];
                float a = W1p[d * 64 + c];
                float b = W1p[(d + 64) * 64 + c];
                su += hv * (a - b);
                sv += hv * b;
            }
            uu[idx] = su + b1p[c];
            vv[idx] = sv;
        }
        __syncthreads();

        for (int idx = tid; idx < Eq * 64; idx += 256) {
            int e = idx >> 6, c = idx & 63;
            hr[idx] = fmaxf(uu[qet[e] * 64 + c] + vv[qes[e] * 64 + c], 0.f);
        }
        __syncthreads();

        {
            int c = tid & 63, e0 = tid >> 6;
            for (int e = e0; e < Eq; e += 4) {
                float acc = 0.f;
#pragma unroll 8
                for (int j = 0; j < 64; ++j)
                    acc += hr[e * 64 + j] * W2s[j * 64 + c];
                me[e * 64 + c] = acc;
            }
        }
        __syncthreads();

        for (int idx = tid; idx < 512; idx += 256) {
            int t = idx >> 6, c = idx & 63;
            float a = -INFINITY;
            for (int e = 0; e < Eq; ++e)
                if (qet[e] == t) a = fmaxf(a, me[e * 64 + c]);
            float vout = (a == -INFINITY) ? 0.f : (a + b2p[c]);
            qx[idx] = fmaxf(vout, 0.f);
        }
        __syncthreads();
    }

    if (tid < 64) {
        float s = 0.f;
        for (int r = 0; r < 8; ++r) s += qx[r * 64 + tid];
        emb[tid] = s;
    }
    __syncthreads();
    if (tid < 8) {
        float o = linb[tid];
        for (int c = 0; c < 64; ++c) o += emb[c] * linW[c * 8 + tid];
        out[tid] = o;
    }
}

// ---------------------------------------------------------------------------
extern "C" void kernel_launch(void* const* d_in, const int* in_sizes, int n_in,
                              void* d_out, int out_size, void* d_ws, size_t ws_size,
                              hipStream_t stream)
{
    const float* x    = (const float*)d_in[0];
    const float* pos  = (const float*)d_in[1];
    const int*   ei   = (const int*)d_in[2];
    const int*   lbl  = (const int*)d_in[3];
    const int*   qei  = (const int*)d_in[4];
    const float* W11 = (const float*)d_in[5];
    const float* b11 = (const float*)d_in[6];
    const float* W12 = (const float*)d_in[7];
    const float* b12 = (const float*)d_in[8];
    const float* W21 = (const float*)d_in[9];
    const float* b21 = (const float*)d_in[10];
    const float* W22 = (const float*)d_in[11];
    const float* b22 = (const float*)d_in[12];
    const float* W31 = (const float*)d_in[13];
    const float* b31 = (const float*)d_in[14];
    const float* W32 = (const float*)d_in[15];
    const float* b32 = (const float*)d_in[16];
    const float* W41 = (const float*)d_in[17];
    const float* b41 = (const float*)d_in[18];
    const float* W42 = (const float*)d_in[19];
    const float* b42 = (const float*)d_in[20];
    const float* linW = (const float*)d_in[21];
    const float* linb = (const float*)d_in[22];

    int N  = in_sizes[0] / 16;          // 100000
    int Eq = in_sizes[4] / 2;           // 32
    const int* src = ei;                // row 0 = src; tgt = repeat(arange(N),16)

    size_t NH = (size_t)N * HDIM;
    unsigned short* hbf = (unsigned short*)d_ws;   // fp16 N*64 (h1)
    unsigned short* Ub  = hbf + NH;                // fp16 N*64
    unsigned short* Vb  = Ub + NH;                 // fp16 N*64
    unsigned short* w2h1 = Vb + NH;
    unsigned short* w2l1 = w2h1 + 4096;
    unsigned short* w2h2 = w2l1 + 4096;
    unsigned short* w2l2 = w2h2 + 4096;
    unsigned short* wph  = w2l2 + 4096;            // 8192
    unsigned short* wpl  = wph + 8192;             // 8192
    float* qsums = (float*)(wpl + 8192);           // 8 banks x 512
    int*   qcnt  = (int*)(qsums + 8 * 512);

    (void)hipMemsetAsync(qsums, 0, 8 * 512 * sizeof(float) + 8 * sizeof(int), stream);

    int nTiles      = N / 16;           // pre_mfma tiles (6250)
    int edgeBlocks  = N / 32;           // edge blocks, 32 nodes each (3125)
    int mainBlocks  = 2048;

    // conv1 (pre1 + fused prep + label histogram)
    pre1_kernel<<<mainBlocks + 32, 256, 0, stream>>>(
        x, pos, W11, b11, Ub, Vb, N, mainBlocks,
        W12, W22, W21, w2h1, w2l1, w2h2, w2l2, wph, wpl, lbl, qcnt);
    edge_mfma_kernel<0><<<edgeBlocks, 256, 0, stream>>>(
        Ub, Vb, src, w2h1, w2l1, b12, hbf, lbl, qsums);
    // conv2
    pre_mfma_kernel<<<1563, 256, 0, stream>>>(hbf, wph, wpl, b21, Ub, Vb, nTiles);
    // conv2 edge + fused region-sum pooling (h2 never materialized)
    edge_mfma_kernel<1><<<edgeBlocks, 256, 0, stream>>>(
        Ub, Vb, src, w2h2, w2l2, b22, hbf, lbl, qsums);
    // quotient tail
    tail_kernel<<<1, 256, 0, stream>>>(qsums, qcnt, qei, Eq,
                                       W31, b31, W32, b32,
                                       W41, b41, W42, b42,
                                       linW, linb, (float*)d_out);
}

// Round 10
// 289.099 us; speedup vs baseline: 1.2011x; 1.0977x over previous
//
#include <hip/hip_runtime.h>
#include <hip/hip_fp16.h>

typedef float fv4 __attribute__((ext_vector_type(4)));
using hf8   = __attribute__((ext_vector_type(8))) _Float16;  // 8 fp16 = 4 VGPRs (MFMA A/B frag)
using f32x4 = __attribute__((ext_vector_type(4))) float;     // MFMA C/D frag
using u32x4 = __attribute__((ext_vector_type(4))) unsigned;
using u32x2 = __attribute__((ext_vector_type(2))) unsigned;

#define HDIM 64
#define QBANKS 64

// fp32 -> fp16 bits (RNE)
__device__ __forceinline__ unsigned short f16r(float f) {
    return __half_as_ushort(__float2half(f));
}
__device__ __forceinline__ float hs2f(unsigned short s) {
    return __half2float(__ushort_as_half(s));
}
// packed fp16: relu(u+v) on 2 channels in one reg (v_pk_add_f16 + v_pk_max_f16)
__device__ __forceinline__ unsigned addrelu2(unsigned ua, unsigned va) {
    unsigned s, r;
    asm("v_pk_add_f16 %0, %1, %2" : "=v"(s) : "v"(ua), "v"(va));
    asm("v_pk_max_f16 %0, %1, 0" : "=v"(r) : "v"(s));
    return r;
}

// ---------------------------------------------------------------------------
// pre1 (+ fused prep + label histogram): blocks < mainBlocks do
//   u = [x|pos] @ (W1a - W1b) + b1 ; v = [x|pos] @ W1b   (D = 19)
// blocks >= mainBlocks: weight split hi/lo + qcnt label histogram.
// (qsums/qcnt zeroed by hipMemsetAsync BEFORE this kernel.)
// ---------------------------------------------------------------------------
__global__ void pre1_kernel(
    const float* __restrict__ x, const float* __restrict__ pos,
    const float* __restrict__ W1, const float* __restrict__ b1,
    unsigned short* __restrict__ U, unsigned short* __restrict__ V, int N,
    int mainBlocks,
    const float* __restrict__ W2a, const float* __restrict__ W2b,
    const float* __restrict__ W1c,
    unsigned short* __restrict__ hiA, unsigned short* __restrict__ loA,
    unsigned short* __restrict__ hiB, unsigned short* __restrict__ loB,
    unsigned short* __restrict__ wph, unsigned short* __restrict__ wpl,
    const int* __restrict__ labels, int* __restrict__ qcnt)
{
    if ((int)blockIdx.x >= mainBlocks) {
        int idx = (blockIdx.x - mainBlocks) * 256 + threadIdx.x;
        if (idx < 4096) {
            int j = idx >> 6, c = idx & 63;
            float w = W2a[idx];
            unsigned short h = f16r(w);
            unsigned short l = f16r(w - hs2f(h));
            hiA[c * 64 + j] = h; loA[c * 64 + j] = l;
            w = W2b[idx];
            h = f16r(w);
            l = f16r(w - hs2f(h));
            hiB[c * 64 + j] = h; loB[c * 64 + j] = l;
        }
        if (idx < 8192) {
            int d = idx & 63, cp = idx >> 6;
            float w = (cp < 64) ? (W1c[d * 64 + cp] - W1c[(d + 64) * 64 + cp])
                                : W1c[(d + 64) * 64 + (cp - 64)];
            unsigned short h = f16r(w);
            unsigned short l = f16r(w - hs2f(h));
            wph[cp * 64 + d] = h;
            wpl[cp * 64 + d] = l;
        }
        // label histogram -> qcnt (8192 threads grid-stride over N)
        {
            __shared__ int lh[8];
            int loc[8] = {0, 0, 0, 0, 0, 0, 0, 0};
            for (int n = idx; n < N; n += 8192) {
                int l = labels[n];
#pragma unroll
                for (int r = 0; r < 8; ++r) loc[r] += (l == r) ? 1 : 0;
            }
            if (threadIdx.x < 8) lh[threadIdx.x] = 0;
            __syncthreads();
#pragma unroll
            for (int r = 0; r < 8; ++r) if (loc[r]) atomicAdd(&lh[r], loc[r]);
            __syncthreads();
            if (threadIdx.x < 8) atomicAdd(&qcnt[threadIdx.x], lh[threadIdx.x]);
        }
        return;
    }

    int lane = threadIdx.x & 63;
    int gw   = (blockIdx.x * blockDim.x + threadIdx.x) >> 6;
    int tw   = (mainBlocks * blockDim.x) >> 6;

    float wd[19], wb[19];
#pragma unroll
    for (int d = 0; d < 19; ++d) {
        float a = W1[d * HDIM + lane];
        float b = W1[(d + 19) * HDIM + lane];
        wd[d] = a - b;
        wb[d] = b;
    }
    float bb = b1[lane];

    for (int n = gw; n < N; n += tw) {
        float su = 0.f, sv = 0.f;
#pragma unroll
        for (int d4 = 0; d4 < 4; ++d4) {
            fv4 h4 = *(const fv4*)&x[(size_t)n * 16 + 4 * d4];
#pragma unroll
            for (int k = 0; k < 4; ++k) {
                su += h4[k] * wd[4 * d4 + k];
                sv += h4[k] * wb[4 * d4 + k];
            }
        }
#pragma unroll
        for (int d = 0; d < 3; ++d) {
            float h = pos[(size_t)n * 3 + d];
            su += h * wd[16 + d];
            sv += h * wb[16 + d];
        }
        U[(size_t)n * HDIM + lane] = f16r(su + bb);
        V[(size_t)n * HDIM + lane] = f16r(sv);
    }
}

// ---------------------------------------------------------------------------
// pre_mfma (conv2 layer-1): [N x 64] @ [64 x 128] on MFMA (fp16).
// OPERAND-SWAPPED: mfma(W, h) so D row = channel, D col = node. Per lane the
// 4 acc elements of one nt are 4 CONSECUTIVE channels of node (base+m)
// -> 8 x 8B stores per tile instead of 32 x 2B.
// ---------------------------------------------------------------------------
__global__ __launch_bounds__(256, 2) void pre_mfma_kernel(
    const unsigned short* __restrict__ h,     // fp16 N x 64
    const unsigned short* __restrict__ Whi,   // fp16 [c' 0..127][d 0..63]
    const unsigned short* __restrict__ Wlo,
    const float* __restrict__ b1,
    unsigned short* __restrict__ U, unsigned short* __restrict__ V, int nTiles)
{
    int lane = threadIdx.x & 63;
    int quad = lane >> 4;
    int m    = lane & 15;
    int gw   = (blockIdx.x * blockDim.x + threadIdx.x) >> 6;
    int tw   = (gridDim.x * blockDim.x) >> 6;

    hf8 Bh[8][2], Bl[8][2];
#pragma unroll
    for (int nt = 0; nt < 8; ++nt)
#pragma unroll
        for (int ks = 0; ks < 2; ++ks) {
            int off = (nt * 16 + m) * 64 + ks * 32 + quad * 8;
            Bh[nt][ks] = *(const hf8*)&Whi[off];
            Bl[nt][ks] = *(const hf8*)&Wlo[off];
        }
    float bias[16];        // [nt][r] = b1[nt*16 + quad*4 + r]
#pragma unroll
    for (int nt = 0; nt < 4; ++nt)
#pragma unroll
        for (int r = 0; r < 4; ++r)
            bias[nt * 4 + r] = b1[nt * 16 + quad * 4 + r];

    for (int t = gw; t < nTiles; t += tw) {
        int base = t * 16;
        hf8 A[2];
#pragma unroll
        for (int ks = 0; ks < 2; ++ks)
            A[ks] = *(const hf8*)&h[(size_t)(base + m) * HDIM + ks * 32 + quad * 8];

        f32x4 acc[8] = {{0,0,0,0},{0,0,0,0},{0,0,0,0},{0,0,0,0},
                        {0,0,0,0},{0,0,0,0},{0,0,0,0},{0,0,0,0}};
#pragma unroll
        for (int ks = 0; ks < 2; ++ks)
#pragma unroll
            for (int nt = 0; nt < 8; ++nt) {
                acc[nt] = __builtin_amdgcn_mfma_f32_16x16x32_f16(Bl[nt][ks], A[ks], acc[nt], 0, 0, 0);
                acc[nt] = __builtin_amdgcn_mfma_f32_16x16x32_f16(Bh[nt][ks], A[ks], acc[nt], 0, 0, 0);
            }

        // lane (quad,m): acc[nt][r] = out[node=base+m][channel nt*16+quad*4+r]
#pragma unroll
        for (int nt = 0; nt < 8; ++nt) {
            unsigned short* __restrict__ dst = (nt < 4) ? U : V;
            int c0 = (nt & 3) * 16 + quad * 4;
            float a0 = acc[nt][0] + ((nt < 4) ? bias[nt * 4 + 0] : 0.f);
            float a1 = acc[nt][1] + ((nt < 4) ? bias[nt * 4 + 1] : 0.f);
            float a2 = acc[nt][2] + ((nt < 4) ? bias[nt * 4 + 2] : 0.f);
            float a3 = acc[nt][3] + ((nt < 4) ? bias[nt * 4 + 3] : 0.f);
            u32x2 pk;
            pk[0] = (unsigned)f16r(a0) | ((unsigned)f16r(a1) << 16);
            pk[1] = (unsigned)f16r(a2) | ((unsigned)f16r(a3) << 16);
            *(u32x2*)&dst[(size_t)(base + m) * HDIM + c0] = pk;
        }
    }
}

// ---------------------------------------------------------------------------
// edge_mfma<POOL>: round-6 verified structure (32 nodes/block, depth-2, two
// static buffer sets, VGPR ~76, no spill). Label loads hoisted before the
// barrier; fold phase has NO memory ops beyond the planned LDS/MFMA mix.
// POOL epilogue (r9 fix): r9's 8-bank global atomics = 256 cache lines x
// ~6250 serialized RMWs each ~= the +31us idle. Now: per-wave plain LDS
// stores into Wsh (free after folds) -> 4-way sum -> 64-bank global atomics
// (2048 lines, ~780 RMWs/line). No DS atomics, one less RMW stage.
// ---------------------------------------------------------------------------
#define FOLD_HALF(V0, V1, OFF)                                                     \
    _Pragma("unroll")                                                              \
    for (int mt = 0; mt < 4; ++mt) {                                               \
        int urow = wave * 8 + (OFF) + mt;                                          \
        u32x4 u0 = *(const u32x4*)((const char*)Ush + urow * 128 + quad * 16);     \
        u32x4 u1 = *(const u32x4*)((const char*)Ush + urow * 128 + 64 + quad * 16);\
        u32x4 a0, a1;                                                              \
        _Pragma("unroll")                                                          \
        for (int p = 0; p < 4; ++p) {                                              \
            a0[p] = addrelu2(u0[p], V0[mt][p]);                                    \
            a1[p] = addrelu2(u1[p], V1[mt][p]);                                    \
        }                                                                          \
        hf8 A0 = __builtin_bit_cast(hf8, a0);                                      \
        hf8 A1 = __builtin_bit_cast(hf8, a1);                                      \
        f32x4 acc[4] = {{0,0,0,0},{0,0,0,0},{0,0,0,0},{0,0,0,0}};                  \
        _Pragma("unroll")                                                          \
        for (int nt = 0; nt < 4; ++nt) {                                           \
            int bb  = nt * 2048 + m * 128 + quad * 16;                             \
            int bs0 = bb ^ ((m & 7) << 4);                                         \
            int bs1 = (bb + 64) ^ ((m & 7) << 4);                                  \
            hf8 Bh0 = *(const hf8*)((const char*)Wsh + bs0);                       \
            hf8 Bl0 = *(const hf8*)((const char*)Wsh + 8192 + bs0);                \
            hf8 Bh1 = *(const hf8*)((const char*)Wsh + bs1);                       \
            hf8 Bl1 = *(const hf8*)((const char*)Wsh + 8192 + bs1);                \
            acc[nt] = __builtin_amdgcn_mfma_f32_16x16x32_f16(A0, Bl0, acc[nt], 0, 0, 0); \
            acc[nt] = __builtin_amdgcn_mfma_f32_16x16x32_f16(A0, Bh0, acc[nt], 0, 0, 0); \
            acc[nt] = __builtin_amdgcn_mfma_f32_16x16x32_f16(A1, Bl1, acc[nt], 0, 0, 0); \
            acc[nt] = __builtin_amdgcn_mfma_f32_16x16x32_f16(A1, Bh1, acc[nt], 0, 0, 0); \
        }                                                                          \
        float mx[4];                                                               \
        _Pragma("unroll")                                                          \
        for (int nt = 0; nt < 4; ++nt)                                             \
            mx[nt] = fmaxf(fmaxf(acc[nt][0], acc[nt][1]), fmaxf(acc[nt][2], acc[nt][3])); \
        _Pragma("unroll")                                                          \
        for (int nt = 0; nt < 4; ++nt) {                                           \
            mx[nt] = fmaxf(mx[nt], __shfl_xor(mx[nt], 16));                        \
            mx[nt] = fmaxf(mx[nt], __shfl_xor(mx[nt], 32));                        \
        }                                                                          \
        float val = (quad == 0) ? mx[0] : (quad == 1) ? mx[1] : (quad == 2) ? mx[2] : mx[3]; \
        float hv = fmaxf(val + b2v, 0.f);                                          \
        if constexpr (POOL) {                                                      \
            int lbl = __shfl(labv, (OFF) + mt);                                    \
            _Pragma("unroll")                                                      \
            for (int r = 0; r < 8; ++r) pacc[r] += (lbl == r) ? hv : 0.f;          \
        } else {                                                                   \
            out[(size_t)(nb + (OFF) + mt) * HDIM + lane] = f16r(hv);               \
        }                                                                          \
    }

template<int POOL>
__global__ __launch_bounds__(256, 3) void edge_mfma_kernel(
    const unsigned short* __restrict__ U, const unsigned short* __restrict__ V,
    const int* __restrict__ src,
    const unsigned short* __restrict__ Whi, const unsigned short* __restrict__ Wlo,
    const float* __restrict__ b2, unsigned short* __restrict__ out,
    const int* __restrict__ labels, float* __restrict__ qsums)
{
    __shared__ __align__(16) unsigned short Wsh[8192];   // 16 KB: hi @0, lo @8192B
    __shared__ __align__(16) unsigned short Ush[2048];   // 4 KB: 32 U rows

    int tid  = threadIdx.x;
    int wave = tid >> 6;
    int lane = tid & 63;
    int quad = lane >> 4;
    int m    = lane & 15;

    int nbB = blockIdx.x * 32;           // block node base
    int nb  = nbB + wave * 8;            // wave's 8 nodes

    // ---- stage W2 hi/lo into LDS with row-XOR swizzle ------------------
#pragma unroll
    for (int it = 0; it < 4; ++it) {
        int chunk = it * 256 + tid;
        int reg   = it >> 1;                  // it 0,1 -> hi ; 2,3 -> lo
        int b     = (chunk & 511) * 16;
        int bs    = b ^ (((b >> 7) & 7) << 4);
        const unsigned short* sp = reg ? Wlo : Whi;
        u32x4 d = *(const u32x4*)((const char*)sp + b);
        *(u32x4*)((char*)Wsh + reg * 8192 + bs) = d;
    }
    // ---- stage block's 32 U rows (contiguous 4 KB) ---------------------
    *(u32x4*)((char*)Ush + tid * 16) =
        *(const u32x4*)((const char*)(U + (size_t)nbB * HDIM) + tid * 16);

    int  srcA = src[(size_t)nb * 16 + lane];
    int  srcB = src[(size_t)(nb + 4) * 16 + lane];
    float b2v = b2[lane];
    float pacc[8] = {0, 0, 0, 0, 0, 0, 0, 0};
    int labv = 0;
    if (POOL && lane < 8) labv = labels[nb + lane];   // hoisted: NOT in fold

    __syncthreads();     // drains everything; placed BEFORE gather issue

    // ---- issue all V gathers: tile A first (older), then tile B --------
    u32x4 vA0[4], vA1[4], vB0[4], vB1[4];
#pragma unroll
    for (int mt = 0; mt < 4; ++mt) {
        int s_ = __shfl(srcA, mt * 16 + m);
        const u32x4* vp = (const u32x4*)(V + (size_t)s_ * HDIM + quad * 8);
        vA0[mt] = vp[0]; vA1[mt] = vp[4];
    }
#pragma unroll
    for (int mt = 0; mt < 4; ++mt) {
        int s_ = __shfl(srcB, mt * 16 + m);
        const u32x4* vp = (const u32x4*)(V + (size_t)s_ * HDIM + quad * 8);
        vB0[mt] = vp[0]; vB1[mt] = vp[4];
    }

    // ---- tile A (B's 8 gathers remain in flight), then tile B ----------
    FOLD_HALF(vA0, vA1, 0)
    FOLD_HALF(vB0, vB1, 4)

    if constexpr (POOL) {
        // reuse Wsh (done after folds): 4 waves x 512 f32 = 8 KB
        float* Wf = (float*)Wsh;
        __syncthreads();                    // all waves done reading Wsh/Ush
#pragma unroll
        for (int r = 0; r < 8; ++r) Wf[wave * 512 + r * 64 + lane] = pacc[r];
        __syncthreads();
        float* qs = qsums + (blockIdx.x & (QBANKS - 1)) * 512;
        for (int idx = tid; idx < 512; idx += 256) {
            float s = Wf[idx] + Wf[512 + idx] + Wf[1024 + idx] + Wf[1536 + idx];
            atomicAdd(&qs[idx], s);
        }
    }
}

// ---------------------------------------------------------------------------
// tail: fully parallel quotient convs (8 nodes, 32 edges) + pool + linear.
// qsums is QBANKS-way banked: sum banks while loading.
// ---------------------------------------------------------------------------
#define EQ_MAX 64
__global__ void tail_kernel(const float* __restrict__ qsums, const int* __restrict__ qcnt,
                            const int* __restrict__ qei, int Eq,
                            const float* __restrict__ W31, const float* __restrict__ b31,
                            const float* __restrict__ W32, const float* __restrict__ b32,
                            const float* __restrict__ W41, const float* __restrict__ b41,
                            const float* __restrict__ W42, const float* __restrict__ b42,
                            const float* __restrict__ linW, const float* __restrict__ linb,
                            float* __restrict__ out)
{
    __shared__ float qx[512], uu[512], vv[512];
    __shared__ float hr[EQ_MAX * 64], me[EQ_MAX * 64];
    __shared__ __align__(16) float W2s[64 * 64];
    __shared__ int   qes[EQ_MAX], qet[EQ_MAX];
    __shared__ float emb[64];

    int tid = threadIdx.x;
    if (Eq > EQ_MAX) Eq = EQ_MAX;

    if (tid < Eq) { qes[tid] = qei[tid]; qet[tid] = qei[Eq + tid]; }
    for (int idx = tid; idx < 512; idx += 256) {
        int r = idx >> 6;
        int cc = qcnt[r];
        float s = 0.f;
        for (int bk = 0; bk < QBANKS; ++bk) s += qsums[bk * 512 + idx];
        qx[idx] = (cc > 0) ? s / (float)cc : 0.f;
    }
    __syncthreads();

    for (int layer = 0; layer < 2; ++layer) {
        const float* W1p = layer ? W41 : W31;
        const float* b1p = layer ? b41 : b31;
        const float* W2p = layer ? W42 : W32;
        const float* b2p = layer ? b42 : b32;

        for (int idx = tid * 4; idx < 4096; idx += 1024)
            *(fv4*)&W2s[idx] = *(const fv4*)&W2p[idx];

        for (int idx = tid; idx < 512; idx += 256) {
            int t = idx >> 6, c = idx & 63;
            float su = 0.f, sv = 0.f;
#pragma unroll 8
            for (int d = 0; d < 64; ++d) {
                float hv = qx[t * 64 + d];
                float a = W1p[d * 64 + c];
                float b = W1p[(d + 64) * 64 + c];
                su += hv * (a - b);
                sv += hv * b;
            }
            uu[idx] = su + b1p[c];
            vv[idx] = sv;
        }
        __syncthreads();

        for (int idx = tid; idx < Eq * 64; idx += 256) {
            int e = idx >> 6, c = idx & 63;
            hr[idx] = fmaxf(uu[qet[e] * 64 + c] + vv[qes[e] * 64 + c], 0.f);
        }
        __syncthreads();

        {
            int c = tid & 63, e0 = tid >> 6;
            for (int e = e0; e < Eq; e += 4) {
                float acc = 0.f;
#pragma unroll 8
                for (int j = 0; j < 64; ++j)
                    acc += hr[e * 64 + j] * W2s[j * 64 + c];
                me[e * 64 + c] = acc;
            }
        }
        __syncthreads();

        for (int idx = tid; idx < 512; idx += 256) {
            int t = idx >> 6, c = idx & 63;
            float a = -INFINITY;
            for (int e = 0; e < Eq; ++e)
                if (qet[e] == t) a = fmaxf(a, me[e * 64 + c]);
            float vout = (a == -INFINITY) ? 0.f : (a + b2p[c]);
            qx[idx] = fmaxf(vout, 0.f);
        }
        __syncthreads();
    }

    if (tid < 64) {
        float s = 0.f;
        for (int r = 0; r < 8; ++r) s += qx[r * 64 + tid];
        emb[tid] = s;
    }
    __syncthreads();
    if (tid < 8) {
        float o = linb[tid];
        for (int c = 0; c < 64; ++c) o += emb[c] * linW[c * 8 + tid];
        out[tid] = o;
    }
}

// ---------------------------------------------------------------------------
extern "C" void kernel_launch(void* const* d_in, const int* in_sizes, int n_in,
                              void* d_out, int out_size, void* d_ws, size_t ws_size,
                              hipStream_t stream)
{
    const float* x    = (const float*)d_in[0];
    const float* pos  = (const float*)d_in[1];
    const int*   ei   = (const int*)d_in[2];
    const int*   lbl  = (const int*)d_in[3];
    const int*   qei  = (const int*)d_in[4];
    const float* W11 = (const float*)d_in[5];
    const float* b11 = (const float*)d_in[6];
    const float* W12 = (const float*)d_in[7];
    const float* b12 = (const float*)d_in[8];
    const float* W21 = (const float*)d_in[9];
    const float* b21 = (const float*)d_in[10];
    const float* W22 = (const float*)d_in[11];
    const float* b22 = (const float*)d_in[12];
    const float* W31 = (const float*)d_in[13];
    const float* b31 = (const float*)d_in[14];
    const float* W32 = (const float*)d_in[15];
    const float* b32 = (const float*)d_in[16];
    const float* W41 = (const float*)d_in[17];
    const float* b41 = (const float*)d_in[18];
    const float* W42 = (const float*)d_in[19];
    const float* b42 = (const float*)d_in[20];
    const float* linW = (const float*)d_in[21];
    const float* linb = (const float*)d_in[22];

    int N  = in_sizes[0] / 16;          // 100000
    int Eq = in_sizes[4] / 2;           // 32
    const int* src = ei;                // row 0 = src; tgt = repeat(arange(N),16)

    size_t NH = (size_t)N * HDIM;
    unsigned short* hbf = (unsigned short*)d_ws;   // fp16 N*64 (h1)
    unsigned short* Ub  = hbf + NH;                // fp16 N*64
    unsigned short* Vb  = Ub + NH;                 // fp16 N*64
    unsigned short* w2h1 = Vb + NH;
    unsigned short* w2l1 = w2h1 + 4096;
    unsigned short* w2h2 = w2l1 + 4096;
    unsigned short* w2l2 = w2h2 + 4096;
    unsigned short* wph  = w2l2 + 4096;            // 8192
    unsigned short* wpl  = wph + 8192;             // 8192
    float* qsums = (float*)(wpl + 8192);           // QBANKS banks x 512
    int*   qcnt  = (int*)(qsums + QBANKS * 512);

    (void)hipMemsetAsync(qsums, 0, QBANKS * 512 * sizeof(float) + 8 * sizeof(int), stream);

    int nTiles      = N / 16;           // pre_mfma tiles (6250)
    int edgeBlocks  = N / 32;           // edge blocks, 32 nodes each (3125)
    int mainBlocks  = 2048;

    // conv1 (pre1 + fused prep + label histogram)
    pre1_kernel<<<mainBlocks + 32, 256, 0, stream>>>(
        x, pos, W11, b11, Ub, Vb, N, mainBlocks,
        W12, W22, W21, w2h1, w2l1, w2h2, w2l2, wph, wpl, lbl, qcnt);
    edge_mfma_kernel<0><<<edgeBlocks, 256, 0, stream>>>(
        Ub, Vb, src, w2h1, w2l1, b12, hbf, lbl, qsums);
    // conv2
    pre_mfma_kernel<<<1563, 256, 0, stream>>>(hbf, wph, wpl, b21, Ub, Vb, nTiles);
    // conv2 edge + fused region-sum pooling (h2 never materialized)
    edge_mfma_kernel<1><<<edgeBlocks, 256, 0, stream>>>(
        Ub, Vb, src, w2h2, w2l2, b22, hbf, lbl, qsums);
    // quotient tail
    tail_kernel<<<1, 256, 0, stream>>>(qsums, qcnt, qei, Eq,
                                       W31, b31, W32, b32,
                                       W41, b41, W42, b42,
                                       linW, linb, (float*)d_out);
}

// Round 11
// 281.478 us; speedup vs baseline: 1.2336x; 1.0271x over previous
//
#include <hip/hip_runtime.h>
#include <hip/hip_fp16.h>

typedef float fv4 __attribute__((ext_vector_type(4)));
using hf8   = __attribute__((ext_vector_type(8))) _Float16;  // 8 fp16 = 4 VGPRs (MFMA A/B frag)
using f32x4 = __attribute__((ext_vector_type(4))) float;     // MFMA C/D frag
using u32x4 = __attribute__((ext_vector_type(4))) unsigned;
using u32x2 = __attribute__((ext_vector_type(2))) unsigned;

#define HDIM 64
#define QBANKS 64

// fp32 -> fp16 bits (RNE)
__device__ __forceinline__ unsigned short f16r(float f) {
    return __half_as_ushort(__float2half(f));
}
__device__ __forceinline__ float hs2f(unsigned short s) {
    return __half2float(__ushort_as_half(s));
}
// packed fp16: relu(u+v) on 2 channels in one reg (v_pk_add_f16 + v_pk_max_f16)
__device__ __forceinline__ unsigned addrelu2(unsigned ua, unsigned va) {
    unsigned s, r;
    asm("v_pk_add_f16 %0, %1, %2" : "=v"(s) : "v"(ua), "v"(va));
    asm("v_pk_max_f16 %0, %1, 0" : "=v"(r) : "v"(s));
    return r;
}

// ---------------------------------------------------------------------------
// pre1 (+ fused prep + label histogram): blocks < mainBlocks do
//   u = [x|pos] @ (W1a - W1b) + b1 ; v = [x|pos] @ W1b   (D = 19)
// blocks >= mainBlocks: weight split hi/lo + qcnt label histogram.
// (qsums/qcnt zeroed by hipMemsetAsync BEFORE this kernel.)
// ---------------------------------------------------------------------------
__global__ void pre1_kernel(
    const float* __restrict__ x, const float* __restrict__ pos,
    const float* __restrict__ W1, const float* __restrict__ b1,
    unsigned short* __restrict__ U, unsigned short* __restrict__ V, int N,
    int mainBlocks,
    const float* __restrict__ W2a, const float* __restrict__ W2b,
    const float* __restrict__ W1c,
    unsigned short* __restrict__ hiA, unsigned short* __restrict__ loA,
    unsigned short* __restrict__ hiB, unsigned short* __restrict__ loB,
    unsigned short* __restrict__ wph, unsigned short* __restrict__ wpl,
    const int* __restrict__ labels, int* __restrict__ qcnt)
{
    if ((int)blockIdx.x >= mainBlocks) {
        int idx = (blockIdx.x - mainBlocks) * 256 + threadIdx.x;
        if (idx < 4096) {
            int j = idx >> 6, c = idx & 63;
            float w = W2a[idx];
            unsigned short h = f16r(w);
            unsigned short l = f16r(w - hs2f(h));
            hiA[c * 64 + j] = h; loA[c * 64 + j] = l;
            w = W2b[idx];
            h = f16r(w);
            l = f16r(w - hs2f(h));
            hiB[c * 64 + j] = h; loB[c * 64 + j] = l;
        }
        if (idx < 8192) {
            int d = idx & 63, cp = idx >> 6;
            float w = (cp < 64) ? (W1c[d * 64 + cp] - W1c[(d + 64) * 64 + cp])
                                : W1c[(d + 64) * 64 + (cp - 64)];
            unsigned short h = f16r(w);
            unsigned short l = f16r(w - hs2f(h));
            wph[cp * 64 + d] = h;
            wpl[cp * 64 + d] = l;
        }
        // label histogram -> qcnt (8192 threads grid-stride over N)
        {
            __shared__ int lh[8];
            int loc[8] = {0, 0, 0, 0, 0, 0, 0, 0};
            for (int n = idx; n < N; n += 8192) {
                int l = labels[n];
#pragma unroll
                for (int r = 0; r < 8; ++r) loc[r] += (l == r) ? 1 : 0;
            }
            if (threadIdx.x < 8) lh[threadIdx.x] = 0;
            __syncthreads();
#pragma unroll
            for (int r = 0; r < 8; ++r) if (loc[r]) atomicAdd(&lh[r], loc[r]);
            __syncthreads();
            if (threadIdx.x < 8) atomicAdd(&qcnt[threadIdx.x], lh[threadIdx.x]);
        }
        return;
    }

    int lane = threadIdx.x & 63;
    int gw   = (blockIdx.x * blockDim.x + threadIdx.x) >> 6;
    int tw   = (mainBlocks * blockDim.x) >> 6;

    float wd[19], wb[19];
#pragma unroll
    for (int d = 0; d < 19; ++d) {
        float a = W1[d * HDIM + lane];
        float b = W1[(d + 19) * HDIM + lane];
        wd[d] = a - b;
        wb[d] = b;
    }
    float bb = b1[lane];

    for (int n = gw; n < N; n += tw) {
        float su = 0.f, sv = 0.f;
#pragma unroll
        for (int d4 = 0; d4 < 4; ++d4) {
            fv4 h4 = *(const fv4*)&x[(size_t)n * 16 + 4 * d4];
#pragma unroll
            for (int k = 0; k < 4; ++k) {
                su += h4[k] * wd[4 * d4 + k];
                sv += h4[k] * wb[4 * d4 + k];
            }
        }
#pragma unroll
        for (int d = 0; d < 3; ++d) {
            float h = pos[(size_t)n * 3 + d];
            su += h * wd[16 + d];
            sv += h * wb[16 + d];
        }
        U[(size_t)n * HDIM + lane] = f16r(su + bb);
        V[(size_t)n * HDIM + lane] = f16r(sv);
    }
}

// ---------------------------------------------------------------------------
// pre_mfma (conv2 layer-1): [N x 64] @ [64 x 128] on MFMA (fp16).
// OPERAND-SWAPPED: mfma(W, h) so D row = channel, D col = node. Per lane the
// 4 acc elements of one nt are 4 CONSECUTIVE channels of node (base+m)
// -> 8 x 8B stores per tile instead of 32 x 2B.
// ---------------------------------------------------------------------------
__global__ __launch_bounds__(256, 2) void pre_mfma_kernel(
    const unsigned short* __restrict__ h,     // fp16 N x 64
    const unsigned short* __restrict__ Whi,   // fp16 [c' 0..127][d 0..63]
    const unsigned short* __restrict__ Wlo,
    const float* __restrict__ b1,
    unsigned short* __restrict__ U, unsigned short* __restrict__ V, int nTiles)
{
    int lane = threadIdx.x & 63;
    int quad = lane >> 4;
    int m    = lane & 15;
    int gw   = (blockIdx.x * blockDim.x + threadIdx.x) >> 6;
    int tw   = (gridDim.x * blockDim.x) >> 6;

    hf8 Bh[8][2], Bl[8][2];
#pragma unroll
    for (int nt = 0; nt < 8; ++nt)
#pragma unroll
        for (int ks = 0; ks < 2; ++ks) {
            int off = (nt * 16 + m) * 64 + ks * 32 + quad * 8;
            Bh[nt][ks] = *(const hf8*)&Whi[off];
            Bl[nt][ks] = *(const hf8*)&Wlo[off];
        }
    float bias[16];        // [nt][r] = b1[nt*16 + quad*4 + r]
#pragma unroll
    for (int nt = 0; nt < 4; ++nt)
#pragma unroll
        for (int r = 0; r < 4; ++r)
            bias[nt * 4 + r] = b1[nt * 16 + quad * 4 + r];

    for (int t = gw; t < nTiles; t += tw) {
        int base = t * 16;
        hf8 A[2];
#pragma unroll
        for (int ks = 0; ks < 2; ++ks)
            A[ks] = *(const hf8*)&h[(size_t)(base + m) * HDIM + ks * 32 + quad * 8];

        f32x4 acc[8] = {{0,0,0,0},{0,0,0,0},{0,0,0,0},{0,0,0,0},
                        {0,0,0,0},{0,0,0,0},{0,0,0,0},{0,0,0,0}};
#pragma unroll
        for (int ks = 0; ks < 2; ++ks)
#pragma unroll
            for (int nt = 0; nt < 8; ++nt) {
                acc[nt] = __builtin_amdgcn_mfma_f32_16x16x32_f16(Bl[nt][ks], A[ks], acc[nt], 0, 0, 0);
                acc[nt] = __builtin_amdgcn_mfma_f32_16x16x32_f16(Bh[nt][ks], A[ks], acc[nt], 0, 0, 0);
            }

        // lane (quad,m): acc[nt][r] = out[node=base+m][channel nt*16+quad*4+r]
#pragma unroll
        for (int nt = 0; nt < 8; ++nt) {
            unsigned short* __restrict__ dst = (nt < 4) ? U : V;
            int c0 = (nt & 3) * 16 + quad * 4;
            float a0 = acc[nt][0] + ((nt < 4) ? bias[nt * 4 + 0] : 0.f);
            float a1 = acc[nt][1] + ((nt < 4) ? bias[nt * 4 + 1] : 0.f);
            float a2 = acc[nt][2] + ((nt < 4) ? bias[nt * 4 + 2] : 0.f);
            float a3 = acc[nt][3] + ((nt < 4) ? bias[nt * 4 + 3] : 0.f);
            u32x2 pk;
            pk[0] = (unsigned)f16r(a0) | ((unsigned)f16r(a1) << 16);
            pk[1] = (unsigned)f16r(a2) | ((unsigned)f16r(a3) << 16);
            *(u32x2*)&dst[(size_t)(base + m) * HDIM + c0] = pk;
        }
    }
}

// ---------------------------------------------------------------------------
// edge_mfma<POOL>: round-6 verified structure (32 nodes/block, depth-2, two
// static buffer sets, VGPR ~76, no spill). Label loads hoisted before the
// barrier; fold phase has NO memory ops beyond the planned LDS/MFMA mix.
// POOL epilogue: per-wave plain LDS stores -> 4-way sum -> 64-bank global
// atomics (2048 lines, ~780 RMWs/line).
// ---------------------------------------------------------------------------
#define FOLD_HALF(V0, V1, OFF)                                                     \
    _Pragma("unroll")                                                              \
    for (int mt = 0; mt < 4; ++mt) {                                               \
        int urow = wave * 8 + (OFF) + mt;                                          \
        u32x4 u0 = *(const u32x4*)((const char*)Ush + urow * 128 + quad * 16);     \
        u32x4 u1 = *(const u32x4*)((const char*)Ush + urow * 128 + 64 + quad * 16);\
        u32x4 a0, a1;                                                              \
        _Pragma("unroll")                                                          \
        for (int p = 0; p < 4; ++p) {                                              \
            a0[p] = addrelu2(u0[p], V0[mt][p]);                                    \
            a1[p] = addrelu2(u1[p], V1[mt][p]);                                    \
        }                                                                          \
        hf8 A0 = __builtin_bit_cast(hf8, a0);                                      \
        hf8 A1 = __builtin_bit_cast(hf8, a1);                                      \
        f32x4 acc[4] = {{0,0,0,0},{0,0,0,0},{0,0,0,0},{0,0,0,0}};                  \
        _Pragma("unroll")                                                          \
        for (int nt = 0; nt < 4; ++nt) {                                           \
            int bb  = nt * 2048 + m * 128 + quad * 16;                             \
            int bs0 = bb ^ ((m & 7) << 4);                                         \
            int bs1 = (bb + 64) ^ ((m & 7) << 4);                                  \
            hf8 Bh0 = *(const hf8*)((const char*)Wsh + bs0);                       \
            hf8 Bl0 = *(const hf8*)((const char*)Wsh + 8192 + bs0);                \
            hf8 Bh1 = *(const hf8*)((const char*)Wsh + bs1);                       \
            hf8 Bl1 = *(const hf8*)((const char*)Wsh + 8192 + bs1);                \
            acc[nt] = __builtin_amdgcn_mfma_f32_16x16x32_f16(A0, Bl0, acc[nt], 0, 0, 0); \
            acc[nt] = __builtin_amdgcn_mfma_f32_16x16x32_f16(A0, Bh0, acc[nt], 0, 0, 0); \
            acc[nt] = __builtin_amdgcn_mfma_f32_16x16x32_f16(A1, Bl1, acc[nt], 0, 0, 0); \
            acc[nt] = __builtin_amdgcn_mfma_f32_16x16x32_f16(A1, Bh1, acc[nt], 0, 0, 0); \
        }                                                                          \
        float mx[4];                                                               \
        _Pragma("unroll")                                                          \
        for (int nt = 0; nt < 4; ++nt)                                             \
            mx[nt] = fmaxf(fmaxf(acc[nt][0], acc[nt][1]), fmaxf(acc[nt][2], acc[nt][3])); \
        _Pragma("unroll")                                                          \
        for (int nt = 0; nt < 4; ++nt) {                                           \
            mx[nt] = fmaxf(mx[nt], __shfl_xor(mx[nt], 16));                        \
            mx[nt] = fmaxf(mx[nt], __shfl_xor(mx[nt], 32));                        \
        }                                                                          \
        float val = (quad == 0) ? mx[0] : (quad == 1) ? mx[1] : (quad == 2) ? mx[2] : mx[3]; \
        float hv = fmaxf(val + b2v, 0.f);                                          \
        if constexpr (POOL) {                                                      \
            int lbl = __shfl(labv, (OFF) + mt);                                    \
            _Pragma("unroll")                                                      \
            for (int r = 0; r < 8; ++r) pacc[r] += (lbl == r) ? hv : 0.f;          \
        } else {                                                                   \
            out[(size_t)(nb + (OFF) + mt) * HDIM + lane] = f16r(hv);               \
        }                                                                          \
    }

template<int POOL>
__global__ __launch_bounds__(256, 3) void edge_mfma_kernel(
    const unsigned short* __restrict__ U, const unsigned short* __restrict__ V,
    const int* __restrict__ src,
    const unsigned short* __restrict__ Whi, const unsigned short* __restrict__ Wlo,
    const float* __restrict__ b2, unsigned short* __restrict__ out,
    const int* __restrict__ labels, float* __restrict__ qsums)
{
    __shared__ __align__(16) unsigned short Wsh[8192];   // 16 KB: hi @0, lo @8192B
    __shared__ __align__(16) unsigned short Ush[2048];   // 4 KB: 32 U rows

    int tid  = threadIdx.x;
    int wave = tid >> 6;
    int lane = tid & 63;
    int quad = lane >> 4;
    int m    = lane & 15;

    int nbB = blockIdx.x * 32;           // block node base
    int nb  = nbB + wave * 8;            // wave's 8 nodes

    // ---- stage W2 hi/lo into LDS with row-XOR swizzle ------------------
#pragma unroll
    for (int it = 0; it < 4; ++it) {
        int chunk = it * 256 + tid;
        int reg   = it >> 1;                  // it 0,1 -> hi ; 2,3 -> lo
        int b     = (chunk & 511) * 16;
        int bs    = b ^ (((b >> 7) & 7) << 4);
        const unsigned short* sp = reg ? Wlo : Whi;
        u32x4 d = *(const u32x4*)((const char*)sp + b);
        *(u32x4*)((char*)Wsh + reg * 8192 + bs) = d;
    }
    // ---- stage block's 32 U rows (contiguous 4 KB) ---------------------
    *(u32x4*)((char*)Ush + tid * 16) =
        *(const u32x4*)((const char*)(U + (size_t)nbB * HDIM) + tid * 16);

    int  srcA = src[(size_t)nb * 16 + lane];
    int  srcB = src[(size_t)(nb + 4) * 16 + lane];
    float b2v = b2[lane];
    float pacc[8] = {0, 0, 0, 0, 0, 0, 0, 0};
    int labv = 0;
    if (POOL && lane < 8) labv = labels[nb + lane];   // hoisted: NOT in fold

    __syncthreads();     // drains everything; placed BEFORE gather issue

    // ---- issue all V gathers: tile A first (older), then tile B --------
    u32x4 vA0[4], vA1[4], vB0[4], vB1[4];
#pragma unroll
    for (int mt = 0; mt < 4; ++mt) {
        int s_ = __shfl(srcA, mt * 16 + m);
        const u32x4* vp = (const u32x4*)(V + (size_t)s_ * HDIM + quad * 8);
        vA0[mt] = vp[0]; vA1[mt] = vp[4];
    }
#pragma unroll
    for (int mt = 0; mt < 4; ++mt) {
        int s_ = __shfl(srcB, mt * 16 + m);
        const u32x4* vp = (const u32x4*)(V + (size_t)s_ * HDIM + quad * 8);
        vB0[mt] = vp[0]; vB1[mt] = vp[4];
    }

    // ---- tile A (B's 8 gathers remain in flight), then tile B ----------
    FOLD_HALF(vA0, vA1, 0)
    FOLD_HALF(vB0, vB1, 4)

    if constexpr (POOL) {
        // reuse Wsh (done after folds): 4 waves x 512 f32 = 8 KB
        float* Wf = (float*)Wsh;
        __syncthreads();                    // all waves done reading Wsh/Ush
#pragma unroll
        for (int r = 0; r < 8; ++r) Wf[wave * 512 + r * 64 + lane] = pacc[r];
        __syncthreads();
        float* qs = qsums + (blockIdx.x & (QBANKS - 1)) * 512;
        for (int idx = tid; idx < 512; idx += 256) {
            float s = Wf[idx] + Wf[512 + idx] + Wf[1024 + idx] + Wf[1536 + idx];
            atomicAdd(&qs[idx], s);
        }
    }
}

// ---------------------------------------------------------------------------
// tail: quotient convs (8 nodes, 32 edges) + pool + linear. 1024 THREADS
// (16 waves on the CU -- r10 showed 55us at 0.03% VALU: single-block latency
// starvation with only 4 waves). Bank-sum and uu/vv GEMM additionally split
// across thread-halves with LDS partial combine.
// ---------------------------------------------------------------------------
#define EQ_MAX 64
__global__ __launch_bounds__(1024) void tail_kernel(
                            const float* __restrict__ qsums, const int* __restrict__ qcnt,
                            const int* __restrict__ qei, int Eq,
                            const float* __restrict__ W31, const float* __restrict__ b31,
                            const float* __restrict__ W32, const float* __restrict__ b32,
                            const float* __restrict__ W41, const float* __restrict__ b41,
                            const float* __restrict__ W42, const float* __restrict__ b42,
                            const float* __restrict__ linW, const float* __restrict__ linb,
                            float* __restrict__ out)
{
    __shared__ float qx[512], uu[512], vv[512];
    __shared__ float hr[EQ_MAX * 64], me[EQ_MAX * 64];
    __shared__ __align__(16) float W2s[64 * 64];
    __shared__ float ps[2048];
    __shared__ int   qes[EQ_MAX], qet[EQ_MAX];
    __shared__ float emb[64];

    int tid = threadIdx.x;
    if (Eq > EQ_MAX) Eq = EQ_MAX;

    if (tid < Eq) { qes[tid] = qei[tid]; qet[tid] = qei[Eq + tid]; }

    // ---- bank sum, parallel over (idx, bank-half) ----------------------
    {
        int idx = tid & 511, half = tid >> 9;
        float s = 0.f;
#pragma unroll
        for (int bk = half * 32; bk < half * 32 + 32; ++bk)
            s += qsums[bk * 512 + idx];
        ps[tid] = s;
    }
    __syncthreads();
    if (tid < 512) {
        int r = tid >> 6;
        int cc = qcnt[r];
        float tot = ps[tid] + ps[512 + tid];
        qx[tid] = (cc > 0) ? tot / (float)cc : 0.f;
    }
    __syncthreads();

    for (int layer = 0; layer < 2; ++layer) {
        const float* W1p = layer ? W41 : W31;
        const float* b1p = layer ? b41 : b31;
        const float* W2p = layer ? W42 : W32;
        const float* b2p = layer ? b42 : b32;

        *(fv4*)&W2s[tid * 4] = *(const fv4*)&W2p[tid * 4];

        // uu/vv GEMM: d-dim split across thread halves, LDS combine
        {
            int idx = tid & 511, half = tid >> 9;
            int t = idx >> 6, c = idx & 63;
            float su = 0.f, sv = 0.f;
#pragma unroll 8
            for (int d = half * 32; d < half * 32 + 32; ++d) {
                float hv = qx[t * 64 + d];
                float a = W1p[d * 64 + c];
                float b = W1p[(d + 64) * 64 + c];
                su += hv * (a - b);
                sv += hv * b;
            }
            ps[tid] = su;
            ps[1024 + tid] = sv;
        }
        __syncthreads();
        if (tid < 512) {
            int c = tid & 63;
            uu[tid] = ps[tid] + ps[512 + tid] + b1p[c];
            vv[tid] = ps[1024 + tid] + ps[1536 + tid];
        }
        __syncthreads();

        for (int idx = tid; idx < Eq * 64; idx += 1024) {
            int e = idx >> 6, c = idx & 63;
            hr[idx] = fmaxf(uu[qet[e] * 64 + c] + vv[qes[e] * 64 + c], 0.f);
        }
        __syncthreads();

        {
            int c = tid & 63, e0 = tid >> 6;       // e0 in 0..15
            for (int e = e0; e < Eq; e += 16) {
                float acc = 0.f;
#pragma unroll 8
                for (int j = 0; j < 64; ++j)
                    acc += hr[e * 64 + j] * W2s[j * 64 + c];
                me[e * 64 + c] = acc;
            }
        }
        __syncthreads();

        if (tid < 512) {
            int t = tid >> 6, c = tid & 63;
            float a = -INFINITY;
            for (int e = 0; e < Eq; ++e)
                if (qet[e] == t) a = fmaxf(a, me[e * 64 + c]);
            float vout = (a == -INFINITY) ? 0.f : (a + b2p[c]);
            qx[tid] = fmaxf(vout, 0.f);
        }
        __syncthreads();
    }

    if (tid < 64) {
        float s = 0.f;
        for (int r = 0; r < 8; ++r) s += qx[r * 64 + tid];
        emb[tid] = s;
    }
    __syncthreads();
    if (tid < 8) {
        float o = linb[tid];
        for (int c = 0; c < 64; ++c) o += emb[c] * linW[c * 8 + tid];
        out[tid] = o;
    }
}

// ---------------------------------------------------------------------------
extern "C" void kernel_launch(void* const* d_in, const int* in_sizes, int n_in,
                              void* d_out, int out_size, void* d_ws, size_t ws_size,
                              hipStream_t stream)
{
    const float* x    = (const float*)d_in[0];
    const float* pos  = (const float*)d_in[1];
    const int*   ei   = (const int*)d_in[2];
    const int*   lbl  = (const int*)d_in[3];
    const int*   qei  = (const int*)d_in[4];
    const float* W11 = (const float*)d_in[5];
    const float* b11 = (const float*)d_in[6];
    const float* W12 = (const float*)d_in[7];
    const float* b12 = (const float*)d_in[8];
    const float* W21 = (const float*)d_in[9];
    const float* b21 = (const float*)d_in[10];
    const float* W22 = (const float*)d_in[11];
    const float* b22 = (const float*)d_in[12];
    const float* W31 = (const float*)d_in[13];
    const float* b31 = (const float*)d_in[14];
    const float* W32 = (const float*)d_in[15];
    const float* b32 = (const float*)d_in[16];
    const float* W41 = (const float*)d_in[17];
    const float* b41 = (const float*)d_in[18];
    const float* W42 = (const float*)d_in[19];
    const float* b42 = (const float*)d_in[20];
    const float* linW = (const float*)d_in[21];
    const float* linb = (const float*)d_in[22];

    int N  = in_sizes[0] / 16;          // 100000
    int Eq = in_sizes[4] / 2;           // 32
    const int* src = ei;                // row 0 = src; tgt = repeat(arange(N),16)

    size_t NH = (size_t)N * HDIM;
    unsigned short* hbf = (unsigned short*)d_ws;   // fp16 N*64 (h1)
    unsigned short* Ub  = hbf + NH;                // fp16 N*64
    unsigned short* Vb  = Ub + NH;                 // fp16 N*64
    unsigned short* w2h1 = Vb + NH;
    unsigned short* w2l1 = w2h1 + 4096;
    unsigned short* w2h2 = w2l1 + 4096;
    unsigned short* w2l2 = w2h2 + 4096;
    unsigned short* wph  = w2l2 + 4096;            // 8192
    unsigned short* wpl  = wph + 8192;             // 8192
    float* qsums = (float*)(wpl + 8192);           // QBANKS banks x 512
    int*   qcnt  = (int*)(qsums + QBANKS * 512);

    (void)hipMemsetAsync(qsums, 0, QBANKS * 512 * sizeof(float) + 8 * sizeof(int), stream);

    int nTiles      = N / 16;           // pre_mfma tiles (6250)
    int edgeBlocks  = N / 32;           // edge blocks, 32 nodes each (3125)
    int mainBlocks  = 2048;

    // conv1 (pre1 + fused prep + label histogram)
    pre1_kernel<<<mainBlocks + 32, 256, 0, stream>>>(
        x, pos, W11, b11, Ub, Vb, N, mainBlocks,
        W12, W22, W21, w2h1, w2l1, w2h2, w2l2, wph, wpl, lbl, qcnt);
    edge_mfma_kernel<0><<<edgeBlocks, 256, 0, stream>>>(
        Ub, Vb, src, w2h1, w2l1, b12, hbf, lbl, qsums);
    // conv2
    pre_mfma_kernel<<<1563, 256, 0, stream>>>(hbf, wph, wpl, b21, Ub, Vb, nTiles);
    // conv2 edge + fused region-sum pooling (h2 never materialized)
    edge_mfma_kernel<1><<<edgeBlocks, 256, 0, stream>>>(
        Ub, Vb, src, w2h2, w2l2, b22, hbf, lbl, qsums);
    // quotient tail
    tail_kernel<<<1, 1024, 0, stream>>>(qsums, qcnt, qei, Eq,
                                        W31, b31, W32, b32,
                                        W41, b41, W42, b42,
                                        linW, linb, (float*)d_out);
}

// Round 12
// 280.056 us; speedup vs baseline: 1.2399x; 1.0051x over previous
//
#include <hip/hip_runtime.h>
#include <hip/hip_fp16.h>

typedef float fv4 __attribute__((ext_vector_type(4)));
using hf8   = __attribute__((ext_vector_type(8))) _Float16;  // 8 fp16 = 4 VGPRs (MFMA A/B frag)
using f32x4 = __attribute__((ext_vector_type(4))) float;     // MFMA C/D frag
using u32x4 = __attribute__((ext_vector_type(4))) unsigned;
using u32x2 = __attribute__((ext_vector_type(2))) unsigned;

#define HDIM 64
#define QBANKS 64

// fp32 -> fp16 bits (RNE)
__device__ __forceinline__ unsigned short f16r(float f) {
    return __half_as_ushort(__float2half(f));
}
__device__ __forceinline__ float hs2f(unsigned short s) {
    return __half2float(__ushort_as_half(s));
}
// packed fp16: relu(u+v) on 2 channels in one reg (v_pk_add_f16 + v_pk_max_f16)
__device__ __forceinline__ unsigned addrelu2(unsigned ua, unsigned va) {
    unsigned s, r;
    asm("v_pk_add_f16 %0, %1, %2" : "=v"(s) : "v"(ua), "v"(va));
    asm("v_pk_max_f16 %0, %1, 0" : "=v"(r) : "v"(s));
    return r;
}

// ---------------------------------------------------------------------------
// pre1 (+ fused prep + label histogram): blocks < mainBlocks do
//   u = [x|pos] @ (W1a - W1b) + b1 ; v = [x|pos] @ W1b   (D = 19)
// 4-NODE UNROLL (r11 fix): pre1 was latency-bound (45.6us, VALU 22%, HBM 9%)
// -- one node per grid-stride iter = serial load->compute chains. Now all
// 28 loads for 4 nodes issue up front; k+1..3 latency hides under k's FMAs.
// All indices compile-time (no scratch). N % 4 == 0 -> no guards.
// blocks >= mainBlocks: weight split hi/lo + qcnt label histogram.
// ---------------------------------------------------------------------------
__global__ void pre1_kernel(
    const float* __restrict__ x, const float* __restrict__ pos,
    const float* __restrict__ W1, const float* __restrict__ b1,
    unsigned short* __restrict__ U, unsigned short* __restrict__ V, int N,
    int mainBlocks,
    const float* __restrict__ W2a, const float* __restrict__ W2b,
    const float* __restrict__ W1c,
    unsigned short* __restrict__ hiA, unsigned short* __restrict__ loA,
    unsigned short* __restrict__ hiB, unsigned short* __restrict__ loB,
    unsigned short* __restrict__ wph, unsigned short* __restrict__ wpl,
    const int* __restrict__ labels, int* __restrict__ qcnt)
{
    if ((int)blockIdx.x >= mainBlocks) {
        int idx = (blockIdx.x - mainBlocks) * 256 + threadIdx.x;
        if (idx < 4096) {
            int j = idx >> 6, c = idx & 63;
            float w = W2a[idx];
            unsigned short h = f16r(w);
            unsigned short l = f16r(w - hs2f(h));
            hiA[c * 64 + j] = h; loA[c * 64 + j] = l;
            w = W2b[idx];
            h = f16r(w);
            l = f16r(w - hs2f(h));
            hiB[c * 64 + j] = h; loB[c * 64 + j] = l;
        }
        if (idx < 8192) {
            int d = idx & 63, cp = idx >> 6;
            float w = (cp < 64) ? (W1c[d * 64 + cp] - W1c[(d + 64) * 64 + cp])
                                : W1c[(d + 64) * 64 + (cp - 64)];
            unsigned short h = f16r(w);
            unsigned short l = f16r(w - hs2f(h));
            wph[cp * 64 + d] = h;
            wpl[cp * 64 + d] = l;
        }
        // label histogram -> qcnt (8192 threads grid-stride over N)
        {
            __shared__ int lh[8];
            int loc[8] = {0, 0, 0, 0, 0, 0, 0, 0};
            for (int n = idx; n < N; n += 8192) {
                int l = labels[n];
#pragma unroll
                for (int r = 0; r < 8; ++r) loc[r] += (l == r) ? 1 : 0;
            }
            if (threadIdx.x < 8) lh[threadIdx.x] = 0;
            __syncthreads();
#pragma unroll
            for (int r = 0; r < 8; ++r) if (loc[r]) atomicAdd(&lh[r], loc[r]);
            __syncthreads();
            if (threadIdx.x < 8) atomicAdd(&qcnt[threadIdx.x], lh[threadIdx.x]);
        }
        return;
    }

    int lane = threadIdx.x & 63;
    int gw   = (blockIdx.x * blockDim.x + threadIdx.x) >> 6;
    int tw   = (mainBlocks * blockDim.x) >> 6;

    float wd[19], wb[19];
#pragma unroll
    for (int d = 0; d < 19; ++d) {
        float a = W1[d * HDIM + lane];
        float b = W1[(d + 19) * HDIM + lane];
        wd[d] = a - b;
        wb[d] = b;
    }
    float bb = b1[lane];

    for (int n0 = gw * 4; n0 < N; n0 += tw * 4) {
        // ---- issue all loads for 4 nodes (MLP) ----
        fv4  xx[4][4];
        float p0[4], p1[4], p2[4];
#pragma unroll
        for (int k = 0; k < 4; ++k) {
#pragma unroll
            for (int d4 = 0; d4 < 4; ++d4)
                xx[k][d4] = *(const fv4*)&x[(size_t)(n0 + k) * 16 + 4 * d4];
            p0[k] = pos[(size_t)(n0 + k) * 3 + 0];
            p1[k] = pos[(size_t)(n0 + k) * 3 + 1];
            p2[k] = pos[(size_t)(n0 + k) * 3 + 2];
        }
        // ---- compute + store 4 nodes ----
#pragma unroll
        for (int k = 0; k < 4; ++k) {
            float su = 0.f, sv = 0.f;
#pragma unroll
            for (int d4 = 0; d4 < 4; ++d4)
#pragma unroll
                for (int q = 0; q < 4; ++q) {
                    su += xx[k][d4][q] * wd[4 * d4 + q];
                    sv += xx[k][d4][q] * wb[4 * d4 + q];
                }
            su += p0[k] * wd[16] + p1[k] * wd[17] + p2[k] * wd[18];
            sv += p0[k] * wb[16] + p1[k] * wb[17] + p2[k] * wb[18];
            U[(size_t)(n0 + k) * HDIM + lane] = f16r(su + bb);
            V[(size_t)(n0 + k) * HDIM + lane] = f16r(sv);
        }
    }
}

// ---------------------------------------------------------------------------
// pre_mfma (conv2 layer-1): [N x 64] @ [64 x 128] on MFMA (fp16).
// OPERAND-SWAPPED: mfma(W, h) so D row = channel, D col = node. Per lane the
// 4 acc elements of one nt are 4 CONSECUTIVE channels of node (base+m)
// -> 8 x 8B stores per tile instead of 32 x 2B.
// ---------------------------------------------------------------------------
__global__ __launch_bounds__(256, 2) void pre_mfma_kernel(
    const unsigned short* __restrict__ h,     // fp16 N x 64
    const unsigned short* __restrict__ Whi,   // fp16 [c' 0..127][d 0..63]
    const unsigned short* __restrict__ Wlo,
    const float* __restrict__ b1,
    unsigned short* __restrict__ U, unsigned short* __restrict__ V, int nTiles)
{
    int lane = threadIdx.x & 63;
    int quad = lane >> 4;
    int m    = lane & 15;
    int gw   = (blockIdx.x * blockDim.x + threadIdx.x) >> 6;
    int tw   = (gridDim.x * blockDim.x) >> 6;

    hf8 Bh[8][2], Bl[8][2];
#pragma unroll
    for (int nt = 0; nt < 8; ++nt)
#pragma unroll
        for (int ks = 0; ks < 2; ++ks) {
            int off = (nt * 16 + m) * 64 + ks * 32 + quad * 8;
            Bh[nt][ks] = *(const hf8*)&Whi[off];
            Bl[nt][ks] = *(const hf8*)&Wlo[off];
        }
    float bias[16];        // [nt][r] = b1[nt*16 + quad*4 + r]
#pragma unroll
    for (int nt = 0; nt < 4; ++nt)
#pragma unroll
        for (int r = 0; r < 4; ++r)
            bias[nt * 4 + r] = b1[nt * 16 + quad * 4 + r];

    for (int t = gw; t < nTiles; t += tw) {
        int base = t * 16;
        hf8 A[2];
#pragma unroll
        for (int ks = 0; ks < 2; ++ks)
            A[ks] = *(const hf8*)&h[(size_t)(base + m) * HDIM + ks * 32 + quad * 8];

        f32x4 acc[8] = {{0,0,0,0},{0,0,0,0},{0,0,0,0},{0,0,0,0},
                        {0,0,0,0},{0,0,0,0},{0,0,0,0},{0,0,0,0}};
#pragma unroll
        for (int ks = 0; ks < 2; ++ks)
#pragma unroll
            for (int nt = 0; nt < 8; ++nt) {
                acc[nt] = __builtin_amdgcn_mfma_f32_16x16x32_f16(Bl[nt][ks], A[ks], acc[nt], 0, 0, 0);
                acc[nt] = __builtin_amdgcn_mfma_f32_16x16x32_f16(Bh[nt][ks], A[ks], acc[nt], 0, 0, 0);
            }

        // lane (quad,m): acc[nt][r] = out[node=base+m][channel nt*16+quad*4+r]
#pragma unroll
        for (int nt = 0; nt < 8; ++nt) {
            unsigned short* __restrict__ dst = (nt < 4) ? U : V;
            int c0 = (nt & 3) * 16 + quad * 4;
            float a0 = acc[nt][0] + ((nt < 4) ? bias[nt * 4 + 0] : 0.f);
            float a1 = acc[nt][1] + ((nt < 4) ? bias[nt * 4 + 1] : 0.f);
            float a2 = acc[nt][2] + ((nt < 4) ? bias[nt * 4 + 2] : 0.f);
            float a3 = acc[nt][3] + ((nt < 4) ? bias[nt * 4 + 3] : 0.f);
            u32x2 pk;
            pk[0] = (unsigned)f16r(a0) | ((unsigned)f16r(a1) << 16);
            pk[1] = (unsigned)f16r(a2) | ((unsigned)f16r(a3) << 16);
            *(u32x2*)&dst[(size_t)(base + m) * HDIM + c0] = pk;
        }
    }
}

// ---------------------------------------------------------------------------
// edge_mfma<POOL>: round-6 verified structure (32 nodes/block, depth-2, two
// static buffer sets, VGPR ~76, no spill). Label loads hoisted before the
// barrier; fold phase has NO memory ops beyond the planned LDS/MFMA mix.
// POOL epilogue: per-wave plain LDS stores -> 4-way sum -> 64-bank global
// atomics (2048 lines, ~780 RMWs/line).
// ---------------------------------------------------------------------------
#define FOLD_HALF(V0, V1, OFF)                                                     \
    _Pragma("unroll")                                                              \
    for (int mt = 0; mt < 4; ++mt) {                                               \
        int urow = wave * 8 + (OFF) + mt;                                          \
        u32x4 u0 = *(const u32x4*)((const char*)Ush + urow * 128 + quad * 16);     \
        u32x4 u1 = *(const u32x4*)((const char*)Ush + urow * 128 + 64 + quad * 16);\
        u32x4 a0, a1;                                                              \
        _Pragma("unroll")                                                          \
        for (int p = 0; p < 4; ++p) {                                              \
            a0[p] = addrelu2(u0[p], V0[mt][p]);                                    \
            a1[p] = addrelu2(u1[p], V1[mt][p]);                                    \
        }                                                                          \
        hf8 A0 = __builtin_bit_cast(hf8, a0);                                      \
        hf8 A1 = __builtin_bit_cast(hf8, a1);                                      \
        f32x4 acc[4] = {{0,0,0,0},{0,0,0,0},{0,0,0,0},{0,0,0,0}};                  \
        _Pragma("unroll")                                                          \
        for (int nt = 0; nt < 4; ++nt) {                                           \
            int bb  = nt * 2048 + m * 128 + quad * 16;                             \
            int bs0 = bb ^ ((m & 7) << 4);                                         \
            int bs1 = (bb + 64) ^ ((m & 7) << 4);                                  \
            hf8 Bh0 = *(const hf8*)((const char*)Wsh + bs0);                       \
            hf8 Bl0 = *(const hf8*)((const char*)Wsh + 8192 + bs0);                \
            hf8 Bh1 = *(const hf8*)((const char*)Wsh + bs1);                       \
            hf8 Bl1 = *(const hf8*)((const char*)Wsh + 8192 + bs1);                \
            acc[nt] = __builtin_amdgcn_mfma_f32_16x16x32_f16(A0, Bl0, acc[nt], 0, 0, 0); \
            acc[nt] = __builtin_amdgcn_mfma_f32_16x16x32_f16(A0, Bh0, acc[nt], 0, 0, 0); \
            acc[nt] = __builtin_amdgcn_mfma_f32_16x16x32_f16(A1, Bl1, acc[nt], 0, 0, 0); \
            acc[nt] = __builtin_amdgcn_mfma_f32_16x16x32_f16(A1, Bh1, acc[nt], 0, 0, 0); \
        }                                                                          \
        float mx[4];                                                               \
        _Pragma("unroll")                                                          \
        for (int nt = 0; nt < 4; ++nt)                                             \
            mx[nt] = fmaxf(fmaxf(acc[nt][0], acc[nt][1]), fmaxf(acc[nt][2], acc[nt][3])); \
        _Pragma("unroll")                                                          \
        for (int nt = 0; nt < 4; ++nt) {                                           \
            mx[nt] = fmaxf(mx[nt], __shfl_xor(mx[nt], 16));                        \
            mx[nt] = fmaxf(mx[nt], __shfl_xor(mx[nt], 32));                        \
        }                                                                          \
        float val = (quad == 0) ? mx[0] : (quad == 1) ? mx[1] : (quad == 2) ? mx[2] : mx[3]; \
        float hv = fmaxf(val + b2v, 0.f);                                          \
        if constexpr (POOL) {                                                      \
            int lbl = __shfl(labv, (OFF) + mt);                                    \
            _Pragma("unroll")                                                      \
            for (int r = 0; r < 8; ++r) pacc[r] += (lbl == r) ? hv : 0.f;          \
        } else {                                                                   \
            out[(size_t)(nb + (OFF) + mt) * HDIM + lane] = f16r(hv);               \
        }                                                                          \
    }

template<int POOL>
__global__ __launch_bounds__(256, 3) void edge_mfma_kernel(
    const unsigned short* __restrict__ U, const unsigned short* __restrict__ V,
    const int* __restrict__ src,
    const unsigned short* __restrict__ Whi, const unsigned short* __restrict__ Wlo,
    const float* __restrict__ b2, unsigned short* __restrict__ out,
    const int* __restrict__ labels, float* __restrict__ qsums)
{
    __shared__ __align__(16) unsigned short Wsh[8192];   // 16 KB: hi @0, lo @8192B
    __shared__ __align__(16) unsigned short Ush[2048];   // 4 KB: 32 U rows

    int tid  = threadIdx.x;
    int wave = tid >> 6;
    int lane = tid & 63;
    int quad = lane >> 4;
    int m    = lane & 15;

    int nbB = blockIdx.x * 32;           // block node base
    int nb  = nbB + wave * 8;            // wave's 8 nodes

    // ---- stage W2 hi/lo into LDS with row-XOR swizzle ------------------
#pragma unroll
    for (int it = 0; it < 4; ++it) {
        int chunk = it * 256 + tid;
        int reg   = it >> 1;                  // it 0,1 -> hi ; 2,3 -> lo
        int b     = (chunk & 511) * 16;
        int bs    = b ^ (((b >> 7) & 7) << 4);
        const unsigned short* sp = reg ? Wlo : Whi;
        u32x4 d = *(const u32x4*)((const char*)sp + b);
        *(u32x4*)((char*)Wsh + reg * 8192 + bs) = d;
    }
    // ---- stage block's 32 U rows (contiguous 4 KB) ---------------------
    *(u32x4*)((char*)Ush + tid * 16) =
        *(const u32x4*)((const char*)(U + (size_t)nbB * HDIM) + tid * 16);

    int  srcA = src[(size_t)nb * 16 + lane];
    int  srcB = src[(size_t)(nb + 4) * 16 + lane];
    float b2v = b2[lane];
    float pacc[8] = {0, 0, 0, 0, 0, 0, 0, 0};
    int labv = 0;
    if (POOL && lane < 8) labv = labels[nb + lane];   // hoisted: NOT in fold

    __syncthreads();     // drains everything; placed BEFORE gather issue

    // ---- issue all V gathers: tile A first (older), then tile B --------
    u32x4 vA0[4], vA1[4], vB0[4], vB1[4];
#pragma unroll
    for (int mt = 0; mt < 4; ++mt) {
        int s_ = __shfl(srcA, mt * 16 + m);
        const u32x4* vp = (const u32x4*)(V + (size_t)s_ * HDIM + quad * 8);
        vA0[mt] = vp[0]; vA1[mt] = vp[4];
    }
#pragma unroll
    for (int mt = 0; mt < 4; ++mt) {
        int s_ = __shfl(srcB, mt * 16 + m);
        const u32x4* vp = (const u32x4*)(V + (size_t)s_ * HDIM + quad * 8);
        vB0[mt] = vp[0]; vB1[mt] = vp[4];
    }

    // ---- tile A (B's 8 gathers remain in flight), then tile B ----------
    FOLD_HALF(vA0, vA1, 0)
    FOLD_HALF(vB0, vB1, 4)

    if constexpr (POOL) {
        // reuse Wsh (done after folds): 4 waves x 512 f32 = 8 KB
        float* Wf = (float*)Wsh;
        __syncthreads();                    // all waves done reading Wsh/Ush
#pragma unroll
        for (int r = 0; r < 8; ++r) Wf[wave * 512 + r * 64 + lane] = pacc[r];
        __syncthreads();
        float* qs = qsums + (blockIdx.x & (QBANKS - 1)) * 512;
        for (int idx = tid; idx < 512; idx += 256) {
            float s = Wf[idx] + Wf[512 + idx] + Wf[1024 + idx] + Wf[1536 + idx];
            atomicAdd(&qs[idx], s);
        }
    }
}

// ---------------------------------------------------------------------------
// tail: quotient convs (8 nodes, 32 edges) + pool + linear. 1024 threads
// (16 waves). Bank-sum and uu/vv GEMM split across thread-halves with LDS
// partial combine.
// ---------------------------------------------------------------------------
#define EQ_MAX 64
__global__ __launch_bounds__(1024) void tail_kernel(
                            const float* __restrict__ qsums, const int* __restrict__ qcnt,
                            const int* __restrict__ qei, int Eq,
                            const float* __restrict__ W31, const float* __restrict__ b31,
                            const float* __restrict__ W32, const float* __restrict__ b32,
                            const float* __restrict__ W41, const float* __restrict__ b41,
                            const float* __restrict__ W42, const float* __restrict__ b42,
                            const float* __restrict__ linW, const float* __restrict__ linb,
                            float* __restrict__ out)
{
    __shared__ float qx[512], uu[512], vv[512];
    __shared__ float hr[EQ_MAX * 64], me[EQ_MAX * 64];
    __shared__ __align__(16) float W2s[64 * 64];
    __shared__ float ps[2048];
    __shared__ int   qes[EQ_MAX], qet[EQ_MAX];
    __shared__ float emb[64];

    int tid = threadIdx.x;
    if (Eq > EQ_MAX) Eq = EQ_MAX;

    if (tid < Eq) { qes[tid] = qei[tid]; qet[tid] = qei[Eq + tid]; }

    // ---- bank sum, parallel over (idx, bank-half) ----------------------
    {
        int idx = tid & 511, half = tid >> 9;
        float s = 0.f;
#pragma unroll
        for (int bk = half * 32; bk < half * 32 + 32; ++bk)
            s += qsums[bk * 512 + idx];
        ps[tid] = s;
    }
    __syncthreads();
    if (tid < 512) {
        int r = tid >> 6;
        int cc = qcnt[r];
        float tot = ps[tid] + ps[512 + tid];
        qx[tid] = (cc > 0) ? tot / (float)cc : 0.f;
    }
    __syncthreads();

    for (int layer = 0; layer < 2; ++layer) {
        const float* W1p = layer ? W41 : W31;
        const float* b1p = layer ? b41 : b31;
        const float* W2p = layer ? W42 : W32;
        const float* b2p = layer ? b42 : b32;

        *(fv4*)&W2s[tid * 4] = *(const fv4*)&W2p[tid * 4];

        // uu/vv GEMM: d-dim split across thread halves, LDS combine
        {
            int idx = tid & 511, half = tid >> 9;
            int t = idx >> 6, c = idx & 63;
            float su = 0.f, sv = 0.f;
#pragma unroll 8
            for (int d = half * 32; d < half * 32 + 32; ++d) {
                float hv = qx[t * 64 + d];
                float a = W1p[d * 64 + c];
                float b = W1p[(d + 64) * 64 + c];
                su += hv * (a - b);
                sv += hv * b;
            }
            ps[tid] = su;
            ps[1024 + tid] = sv;
        }
        __syncthreads();
        if (tid < 512) {
            int c = tid & 63;
            uu[tid] = ps[tid] + ps[512 + tid] + b1p[c];
            vv[tid] = ps[1024 + tid] + ps[1536 + tid];
        }
        __syncthreads();

        for (int idx = tid; idx < Eq * 64; idx += 1024) {
            int e = idx >> 6, c = idx & 63;
            hr[idx] = fmaxf(uu[qet[e] * 64 + c] + vv[qes[e] * 64 + c], 0.f);
        }
        __syncthreads();

        {
            int c = tid & 63, e0 = tid >> 6;       // e0 in 0..15
            for (int e = e0; e < Eq; e += 16) {
                float acc = 0.f;
#pragma unroll 8
                for (int j = 0; j < 64; ++j)
                    acc += hr[e * 64 + j] * W2s[j * 64 + c];
                me[e * 64 + c] = acc;
            }
        }
        __syncthreads();

        if (tid < 512) {
            int t = tid >> 6, c = tid & 63;
            float a = -INFINITY;
            for (int e = 0; e < Eq; ++e)
                if (qet[e] == t) a = fmaxf(a, me[e * 64 + c]);
            float vout = (a == -INFINITY) ? 0.f : (a + b2p[c]);
            qx[tid] = fmaxf(vout, 0.f);
        }
        __syncthreads();
    }

    if (tid < 64) {
        float s = 0.f;
        for (int r = 0; r < 8; ++r) s += qx[r * 64 + tid];
        emb[tid] = s;
    }
    __syncthreads();
    if (tid < 8) {
        float o = linb[tid];
        for (int c = 0; c < 64; ++c) o += emb[c] * linW[c * 8 + tid];
        out[tid] = o;
    }
}

// ---------------------------------------------------------------------------
extern "C" void kernel_launch(void* const* d_in, const int* in_sizes, int n_in,
                              void* d_out, int out_size, void* d_ws, size_t ws_size,
                              hipStream_t stream)
{
    const float* x    = (const float*)d_in[0];
    const float* pos  = (const float*)d_in[1];
    const int*   ei   = (const int*)d_in[2];
    const int*   lbl  = (const int*)d_in[3];
    const int*   qei  = (const int*)d_in[4];
    const float* W11 = (const float*)d_in[5];
    const float* b11 = (const float*)d_in[6];
    const float* W12 = (const float*)d_in[7];
    const float* b12 = (const float*)d_in[8];
    const float* W21 = (const float*)d_in[9];
    const float* b21 = (const float*)d_in[10];
    const float* W22 = (const float*)d_in[11];
    const float* b22 = (const float*)d_in[12];
    const float* W31 = (const float*)d_in[13];
    const float* b31 = (const float*)d_in[14];
    const float* W32 = (const float*)d_in[15];
    const float* b32 = (const float*)d_in[16];
    const float* W41 = (const float*)d_in[17];
    const float* b41 = (const float*)d_in[18];
    const float* W42 = (const float*)d_in[19];
    const float* b42 = (const float*)d_in[20];
    const float* linW = (const float*)d_in[21];
    const float* linb = (const float*)d_in[22];

    int N  = in_sizes[0] / 16;          // 100000
    int Eq = in_sizes[4] / 2;           // 32
    const int* src = ei;                // row 0 = src; tgt = repeat(arange(N),16)

    size_t NH = (size_t)N * HDIM;
    unsigned short* hbf = (unsigned short*)d_ws;   // fp16 N*64 (h1)
    unsigned short* Ub  = hbf + NH;                // fp16 N*64
    unsigned short* Vb  = Ub + NH;                 // fp16 N*64
    unsigned short* w2h1 = Vb + NH;
    unsigned short* w2l1 = w2h1 + 4096;
    unsigned short* w2h2 = w2l1 + 4096;
    unsigned short* w2l2 = w2h2 + 4096;
    unsigned short* wph  = w2l2 + 4096;            // 8192
    unsigned short* wpl  = wph + 8192;             // 8192
    float* qsums = (float*)(wpl + 8192);           // QBANKS banks x 512
    int*   qcnt  = (int*)(qsums + QBANKS * 512);

    (void)hipMemsetAsync(qsums, 0, QBANKS * 512 * sizeof(float) + 8 * sizeof(int), stream);

    int nTiles      = N / 16;           // pre_mfma tiles (6250)
    int edgeBlocks  = N / 32;           // edge blocks, 32 nodes each (3125)
    int mainBlocks  = 2048;

    // conv1 (pre1 + fused prep + label histogram)
    pre1_kernel<<<mainBlocks + 32, 256, 0, stream>>>(
        x, pos, W11, b11, Ub, Vb, N, mainBlocks,
        W12, W22, W21, w2h1, w2l1, w2h2, w2l2, wph, wpl, lbl, qcnt);
    edge_mfma_kernel<0><<<edgeBlocks, 256, 0, stream>>>(
        Ub, Vb, src, w2h1, w2l1, b12, hbf, lbl, qsums);
    // conv2
    pre_mfma_kernel<<<1563, 256, 0, stream>>>(hbf, wph, wpl, b21, Ub, Vb, nTiles);
    // conv2 edge + fused region-sum pooling (h2 never materialized)
    edge_mfma_kernel<1><<<edgeBlocks, 256, 0, stream>>>(
        Ub, Vb, src, w2h2, w2l2, b22, hbf, lbl, qsums);
    // quotient tail
    tail_kernel<<<1, 1024, 0, stream>>>(qsums, qcnt, qei, Eq,
                                        W31, b31, W32, b32,
                                        W41, b41, W42, b42,
                                        linW, linb, (float*)d_out);
}

// Round 13
// 273.239 us; speedup vs baseline: 1.2708x; 1.0249x over previous
//
#include <hip/hip_runtime.h>
#include <hip/hip_fp16.h>

typedef float fv4 __attribute__((ext_vector_type(4)));
using hf8   = __attribute__((ext_vector_type(8))) _Float16;  // 8 fp16 = 4 VGPRs (MFMA A/B frag)
using f32x4 = __attribute__((ext_vector_type(4))) float;     // MFMA C/D frag
using u32x4 = __attribute__((ext_vector_type(4))) unsigned;
using u32x2 = __attribute__((ext_vector_type(2))) unsigned;

#define HDIM 64
#define QBANKS 64

// fp32 -> fp16 bits (RNE)
__device__ __forceinline__ unsigned short f16r(float f) {
    return __half_as_ushort(__float2half(f));
}
__device__ __forceinline__ float hs2f(unsigned short s) {
    return __half2float(__ushort_as_half(s));
}
// packed fp16: relu(u+v) on 2 channels in one reg (v_pk_add_f16 + v_pk_max_f16)
__device__ __forceinline__ unsigned addrelu2(unsigned ua, unsigned va) {
    unsigned s, r;
    asm("v_pk_add_f16 %0, %1, %2" : "=v"(s) : "v"(ua), "v"(va));
    asm("v_pk_max_f16 %0, %1, 0" : "=v"(r) : "v"(s));
    return r;
}

// ---------------------------------------------------------------------------
// pre1 (+ fused prep + label histogram): blocks < mainBlocks do
//   u = [x|pos] @ (W1a - W1b) + b1 ; v = [x|pos] @ W1b   (D = 19)
// blocks >= mainBlocks: weight split hi/lo + qcnt label histogram.
// ---------------------------------------------------------------------------
__global__ void pre1_kernel(
    const float* __restrict__ x, const float* __restrict__ pos,
    const float* __restrict__ W1, const float* __restrict__ b1,
    unsigned short* __restrict__ U, unsigned short* __restrict__ V, int N,
    int mainBlocks,
    const float* __restrict__ W2a, const float* __restrict__ W2b,
    const float* __restrict__ W1c,
    unsigned short* __restrict__ hiA, unsigned short* __restrict__ loA,
    unsigned short* __restrict__ hiB, unsigned short* __restrict__ loB,
    unsigned short* __restrict__ wph, unsigned short* __restrict__ wpl,
    const int* __restrict__ labels, int* __restrict__ qcnt)
{
    if ((int)blockIdx.x >= mainBlocks) {
        int idx = (blockIdx.x - mainBlocks) * 256 + threadIdx.x;
        if (idx < 4096) {
            int j = idx >> 6, c = idx & 63;
            float w = W2a[idx];
            unsigned short h = f16r(w);
            unsigned short l = f16r(w - hs2f(h));
            hiA[c * 64 + j] = h; loA[c * 64 + j] = l;
            w = W2b[idx];
            h = f16r(w);
            l = f16r(w - hs2f(h));
            hiB[c * 64 + j] = h; loB[c * 64 + j] = l;
        }
        if (idx < 8192) {
            int d = idx & 63, cp = idx >> 6;
            float w = (cp < 64) ? (W1c[d * 64 + cp] - W1c[(d + 64) * 64 + cp])
                                : W1c[(d + 64) * 64 + (cp - 64)];
            unsigned short h = f16r(w);
            unsigned short l = f16r(w - hs2f(h));
            wph[cp * 64 + d] = h;
            wpl[cp * 64 + d] = l;
        }
        // label histogram -> qcnt (8192 threads grid-stride over N)
        {
            __shared__ int lh[8];
            int loc[8] = {0, 0, 0, 0, 0, 0, 0, 0};
            for (int n = idx; n < N; n += 8192) {
                int l = labels[n];
#pragma unroll
                for (int r = 0; r < 8; ++r) loc[r] += (l == r) ? 1 : 0;
            }
            if (threadIdx.x < 8) lh[threadIdx.x] = 0;
            __syncthreads();
#pragma unroll
            for (int r = 0; r < 8; ++r) if (loc[r]) atomicAdd(&lh[r], loc[r]);
            __syncthreads();
            if (threadIdx.x < 8) atomicAdd(&qcnt[threadIdx.x], lh[threadIdx.x]);
        }
        return;
    }

    int lane = threadIdx.x & 63;
    int gw   = (blockIdx.x * blockDim.x + threadIdx.x) >> 6;
    int tw   = (mainBlocks * blockDim.x) >> 6;

    float wd[19], wb[19];
#pragma unroll
    for (int d = 0; d < 19; ++d) {
        float a = W1[d * HDIM + lane];
        float b = W1[(d + 19) * HDIM + lane];
        wd[d] = a - b;
        wb[d] = b;
    }
    float bb = b1[lane];

    for (int n0 = gw * 4; n0 < N; n0 += tw * 4) {
        fv4  xx[4][4];
        float p0[4], p1[4], p2[4];
#pragma unroll
        for (int k = 0; k < 4; ++k) {
#pragma unroll
            for (int d4 = 0; d4 < 4; ++d4)
                xx[k][d4] = *(const fv4*)&x[(size_t)(n0 + k) * 16 + 4 * d4];
            p0[k] = pos[(size_t)(n0 + k) * 3 + 0];
            p1[k] = pos[(size_t)(n0 + k) * 3 + 1];
            p2[k] = pos[(size_t)(n0 + k) * 3 + 2];
        }
#pragma unroll
        for (int k = 0; k < 4; ++k) {
            float su = 0.f, sv = 0.f;
#pragma unroll
            for (int d4 = 0; d4 < 4; ++d4)
#pragma unroll
                for (int q = 0; q < 4; ++q) {
                    su += xx[k][d4][q] * wd[4 * d4 + q];
                    sv += xx[k][d4][q] * wb[4 * d4 + q];
                }
            su += p0[k] * wd[16] + p1[k] * wd[17] + p2[k] * wd[18];
            sv += p0[k] * wb[16] + p1[k] * wb[17] + p2[k] * wb[18];
            U[(size_t)(n0 + k) * HDIM + lane] = f16r(su + bb);
            V[(size_t)(n0 + k) * HDIM + lane] = f16r(sv);
        }
    }
}

// ---------------------------------------------------------------------------
// pre_mfma (fallback path only, when ws too small for fusion).
// OPERAND-SWAPPED: mfma(W, h) so D row = channel, D col = node.
// ---------------------------------------------------------------------------
__global__ __launch_bounds__(256, 2) void pre_mfma_kernel(
    const unsigned short* __restrict__ h,
    const unsigned short* __restrict__ Whi,   // fp16 [c' 0..127][d 0..63]
    const unsigned short* __restrict__ Wlo,
    const float* __restrict__ b1,
    unsigned short* __restrict__ U, unsigned short* __restrict__ V, int nTiles)
{
    int lane = threadIdx.x & 63;
    int quad = lane >> 4;
    int m    = lane & 15;
    int gw   = (blockIdx.x * blockDim.x + threadIdx.x) >> 6;
    int tw   = (gridDim.x * blockDim.x) >> 6;

    hf8 Bh[8][2], Bl[8][2];
#pragma unroll
    for (int nt = 0; nt < 8; ++nt)
#pragma unroll
        for (int ks = 0; ks < 2; ++ks) {
            int off = (nt * 16 + m) * 64 + ks * 32 + quad * 8;
            Bh[nt][ks] = *(const hf8*)&Whi[off];
            Bl[nt][ks] = *(const hf8*)&Wlo[off];
        }
    float bias[16];
#pragma unroll
    for (int nt = 0; nt < 4; ++nt)
#pragma unroll
        for (int r = 0; r < 4; ++r)
            bias[nt * 4 + r] = b1[nt * 16 + quad * 4 + r];

    for (int t = gw; t < nTiles; t += tw) {
        int base = t * 16;
        hf8 A[2];
#pragma unroll
        for (int ks = 0; ks < 2; ++ks)
            A[ks] = *(const hf8*)&h[(size_t)(base + m) * HDIM + ks * 32 + quad * 8];

        f32x4 acc[8] = {{0,0,0,0},{0,0,0,0},{0,0,0,0},{0,0,0,0},
                        {0,0,0,0},{0,0,0,0},{0,0,0,0},{0,0,0,0}};
#pragma unroll
        for (int ks = 0; ks < 2; ++ks)
#pragma unroll
            for (int nt = 0; nt < 8; ++nt) {
                acc[nt] = __builtin_amdgcn_mfma_f32_16x16x32_f16(Bl[nt][ks], A[ks], acc[nt], 0, 0, 0);
                acc[nt] = __builtin_amdgcn_mfma_f32_16x16x32_f16(Bh[nt][ks], A[ks], acc[nt], 0, 0, 0);
            }

#pragma unroll
        for (int nt = 0; nt < 8; ++nt) {
            unsigned short* __restrict__ dst = (nt < 4) ? U : V;
            int c0 = (nt & 3) * 16 + quad * 4;
            float a0 = acc[nt][0] + ((nt < 4) ? bias[nt * 4 + 0] : 0.f);
            float a1 = acc[nt][1] + ((nt < 4) ? bias[nt * 4 + 1] : 0.f);
            float a2 = acc[nt][2] + ((nt < 4) ? bias[nt * 4 + 2] : 0.f);
            float a3 = acc[nt][3] + ((nt < 4) ? bias[nt * 4 + 3] : 0.f);
            u32x2 pk;
            pk[0] = (unsigned)f16r(a0) | ((unsigned)f16r(a1) << 16);
            pk[1] = (unsigned)f16r(a2) | ((unsigned)f16r(a3) << 16);
            *(u32x2*)&dst[(size_t)(base + m) * HDIM + c0] = pk;
        }
    }
}

// ---------------------------------------------------------------------------
// edge_mfma<MODE>: round-6 verified fold structure (32 nodes/block, depth-2,
// two static buffer sets). MODE=0: store h to global (fallback). MODE=1:
// POOL region-sum epilogue (conv2 edge). MODE=2: FUSED -- the h-store goes
// to swizzled LDS (replacing the global store, wave-private rows), then after
// a barrier each wave runs the pre_mfma operand-swapped MFMA for its
// tile/half and writes conv2's U2/V2 directly. Eliminates the pre_mfma
// dispatch and h1's 25MB global round-trip.
// ---------------------------------------------------------------------------
#define FOLD_HALF(V0, V1, OFF)                                                     \
    _Pragma("unroll")                                                              \
    for (int mt = 0; mt < 4; ++mt) {                                               \
        int urow = wave * 8 + (OFF) + mt;                                          \
        u32x4 u0 = *(const u32x4*)((const char*)Ush + urow * 128 + quad * 16);     \
        u32x4 u1 = *(const u32x4*)((const char*)Ush + urow * 128 + 64 + quad * 16);\
        u32x4 a0, a1;                                                              \
        _Pragma("unroll")                                                          \
        for (int p = 0; p < 4; ++p) {                                              \
            a0[p] = addrelu2(u0[p], V0[mt][p]);                                    \
            a1[p] = addrelu2(u1[p], V1[mt][p]);                                    \
        }                                                                          \
        hf8 A0 = __builtin_bit_cast(hf8, a0);                                      \
        hf8 A1 = __builtin_bit_cast(hf8, a1);                                      \
        f32x4 acc[4] = {{0,0,0,0},{0,0,0,0},{0,0,0,0},{0,0,0,0}};                  \
        _Pragma("unroll")                                                          \
        for (int nt = 0; nt < 4; ++nt) {                                           \
            int bb  = nt * 2048 + m * 128 + quad * 16;                             \
            int bs0 = bb ^ ((m & 7) << 4);                                         \
            int bs1 = (bb + 64) ^ ((m & 7) << 4);                                  \
            hf8 Bh0 = *(const hf8*)((const char*)Wsh + bs0);                       \
            hf8 Bl0 = *(const hf8*)((const char*)Wsh + 8192 + bs0);                \
            hf8 Bh1 = *(const hf8*)((const char*)Wsh + bs1);                       \
            hf8 Bl1 = *(const hf8*)((const char*)Wsh + 8192 + bs1);                \
            acc[nt] = __builtin_amdgcn_mfma_f32_16x16x32_f16(A0, Bl0, acc[nt], 0, 0, 0); \
            acc[nt] = __builtin_amdgcn_mfma_f32_16x16x32_f16(A0, Bh0, acc[nt], 0, 0, 0); \
            acc[nt] = __builtin_amdgcn_mfma_f32_16x16x32_f16(A1, Bl1, acc[nt], 0, 0, 0); \
            acc[nt] = __builtin_amdgcn_mfma_f32_16x16x32_f16(A1, Bh1, acc[nt], 0, 0, 0); \
        }                                                                          \
        float mx[4];                                                               \
        _Pragma("unroll")                                                          \
        for (int nt = 0; nt < 4; ++nt)                                             \
            mx[nt] = fmaxf(fmaxf(acc[nt][0], acc[nt][1]), fmaxf(acc[nt][2], acc[nt][3])); \
        _Pragma("unroll")                                                          \
        for (int nt = 0; nt < 4; ++nt) {                                           \
            mx[nt] = fmaxf(mx[nt], __shfl_xor(mx[nt], 16));                        \
            mx[nt] = fmaxf(mx[nt], __shfl_xor(mx[nt], 32));                        \
        }                                                                          \
        float val = (quad == 0) ? mx[0] : (quad == 1) ? mx[1] : (quad == 2) ? mx[2] : mx[3]; \
        float hv = fmaxf(val + b2v, 0.f);                                          \
        if constexpr (MODE == 1) {                                                 \
            int lbl = __shfl(labv, (OFF) + mt);                                    \
            _Pragma("unroll")                                                      \
            for (int r = 0; r < 8; ++r) pacc[r] += (lbl == r) ? hv : 0.f;          \
        } else if constexpr (MODE == 2) {                                          \
            int wbyte = urow * 128 + ((lane * 2) ^ ((urow & 7) << 4));             \
            *(unsigned short*)((char*)Ush + wbyte) = f16r(hv);                     \
        } else {                                                                   \
            out[(size_t)(nb + (OFF) + mt) * HDIM + lane] = f16r(hv);               \
        }                                                                          \
    }

template<int MODE>
__global__ __launch_bounds__(256, 3) void edge_mfma_kernel(
    const unsigned short* __restrict__ U, const unsigned short* __restrict__ V,
    const int* __restrict__ src,
    const unsigned short* __restrict__ Whi, const unsigned short* __restrict__ Wlo,
    const float* __restrict__ b2, unsigned short* __restrict__ out,
    const int* __restrict__ labels, float* __restrict__ qsums,
    const unsigned short* __restrict__ Wp_hi, const unsigned short* __restrict__ Wp_lo,
    const float* __restrict__ b1n,
    unsigned short* __restrict__ U2, unsigned short* __restrict__ V2)
{
    __shared__ __align__(16) unsigned short Wsh[8192];   // 16 KB: hi @0, lo @8192B
    __shared__ __align__(16) unsigned short Ush[2048];   // 4 KB: 32 U rows -> 32 h rows (MODE 2)

    int tid  = threadIdx.x;
    int wave = tid >> 6;
    int lane = tid & 63;
    int quad = lane >> 4;
    int m    = lane & 15;

    int nbB = blockIdx.x * 32;           // block node base
    int nb  = nbB + wave * 8;            // wave's 8 nodes

    // ---- stage W2 hi/lo into LDS with row-XOR swizzle ------------------
#pragma unroll
    for (int it = 0; it < 4; ++it) {
        int chunk = it * 256 + tid;
        int reg   = it >> 1;                  // it 0,1 -> hi ; 2,3 -> lo
        int b     = (chunk & 511) * 16;
        int bs    = b ^ (((b >> 7) & 7) << 4);
        const unsigned short* sp = reg ? Wlo : Whi;
        u32x4 d = *(const u32x4*)((const char*)sp + b);
        *(u32x4*)((char*)Wsh + reg * 8192 + bs) = d;
    }
    // ---- stage block's 32 U rows (contiguous 4 KB) ---------------------
    *(u32x4*)((char*)Ush + tid * 16) =
        *(const u32x4*)((const char*)(U + (size_t)nbB * HDIM) + tid * 16);

    int  srcA = src[(size_t)nb * 16 + lane];
    int  srcB = src[(size_t)(nb + 4) * 16 + lane];
    float b2v = b2[lane];
    float pacc[8] = {0, 0, 0, 0, 0, 0, 0, 0};
    int labv = 0;
    if (MODE == 1 && lane < 8) labv = labels[nb + lane];   // hoisted: NOT in fold

    __syncthreads();     // drains everything; placed BEFORE gather issue

    // ---- issue all V gathers: tile A first (older), then tile B --------
    u32x4 vA0[4], vA1[4], vB0[4], vB1[4];
#pragma unroll
    for (int mt = 0; mt < 4; ++mt) {
        int s_ = __shfl(srcA, mt * 16 + m);
        const u32x4* vp = (const u32x4*)(V + (size_t)s_ * HDIM + quad * 8);
        vA0[mt] = vp[0]; vA1[mt] = vp[4];
    }
#pragma unroll
    for (int mt = 0; mt < 4; ++mt) {
        int s_ = __shfl(srcB, mt * 16 + m);
        const u32x4* vp = (const u32x4*)(V + (size_t)s_ * HDIM + quad * 8);
        vB0[mt] = vp[0]; vB1[mt] = vp[4];
    }

    // ---- tile A (B's 8 gathers remain in flight), then tile B ----------
    FOLD_HALF(vA0, vA1, 0)
    FOLD_HALF(vB0, vB1, 4)

    if constexpr (MODE == 1) {
        // reuse Wsh (done after folds): 4 waves x 512 f32 = 8 KB
        float* Wf = (float*)Wsh;
        __syncthreads();                    // all waves done reading Wsh/Ush
#pragma unroll
        for (int r = 0; r < 8; ++r) Wf[wave * 512 + r * 64 + lane] = pacc[r];
        __syncthreads();
        float* qs = qsums + (blockIdx.x & (QBANKS - 1)) * 512;
        for (int idx = tid; idx < 512; idx += 256) {
            float s = Wf[idx] + Wf[512 + idx] + Wf[1024 + idx] + Wf[1536 + idx];
            atomicAdd(&qs[idx], s);
        }
    }

    if constexpr (MODE == 2) {
        __syncthreads();                    // all 32 h rows visible in Ush
        int tile = wave >> 1;               // 0..1 (16 nodes each)
        int hh2  = wave & 1;                // 0 -> U' (c' 0..63), 1 -> V'
        int base = nbB + tile * 16;
        int rowA = tile * 16 + m;
        int xr   = (rowA & 7) << 4;
        hf8 A0f = *(const hf8*)((const char*)Ush + rowA * 128 + ((quad * 16) ^ xr));
        hf8 A1f = *(const hf8*)((const char*)Ush + rowA * 128 + ((64 + quad * 16) ^ xr));

        hf8 Wh_[4][2], Wl_[4][2];
#pragma unroll
        for (int j = 0; j < 4; ++j)
#pragma unroll
            for (int ks = 0; ks < 2; ++ks) {
                int off = ((hh2 * 4 + j) * 16 + m) * 64 + ks * 32 + quad * 8;
                Wh_[j][ks] = *(const hf8*)&Wp_hi[off];
                Wl_[j][ks] = *(const hf8*)&Wp_lo[off];
            }
        f32x4 acc2[4] = {{0,0,0,0},{0,0,0,0},{0,0,0,0},{0,0,0,0}};
#pragma unroll
        for (int j = 0; j < 4; ++j) {
            acc2[j] = __builtin_amdgcn_mfma_f32_16x16x32_f16(Wl_[j][0], A0f, acc2[j], 0, 0, 0);
            acc2[j] = __builtin_amdgcn_mfma_f32_16x16x32_f16(Wh_[j][0], A0f, acc2[j], 0, 0, 0);
            acc2[j] = __builtin_amdgcn_mfma_f32_16x16x32_f16(Wl_[j][1], A1f, acc2[j], 0, 0, 0);
            acc2[j] = __builtin_amdgcn_mfma_f32_16x16x32_f16(Wh_[j][1], A1f, acc2[j], 0, 0, 0);
        }
        unsigned short* __restrict__ dst2 = hh2 ? V2 : U2;
#pragma unroll
        for (int j = 0; j < 4; ++j) {
            int c0 = j * 16 + quad * 4;
            float a0 = acc2[j][0], a1 = acc2[j][1], a2 = acc2[j][2], a3 = acc2[j][3];
            if (hh2 == 0) {
                a0 += b1n[c0 + 0]; a1 += b1n[c0 + 1];
                a2 += b1n[c0 + 2]; a3 += b1n[c0 + 3];
            }
            u32x2 pk;
            pk[0] = (unsigned)f16r(a0) | ((unsigned)f16r(a1) << 16);
            pk[1] = (unsigned)f16r(a2) | ((unsigned)f16r(a3) << 16);
            *(u32x2*)&dst2[(size_t)(base + m) * HDIM + c0] = pk;
        }
    }
}

// ---------------------------------------------------------------------------
// tail: quotient convs (8 nodes, 32 edges) + pool + linear. 1024 threads.
// ---------------------------------------------------------------------------
#define EQ_MAX 64
__global__ __launch_bounds__(1024) void tail_kernel(
                            const float* __restrict__ qsums, const int* __restrict__ qcnt,
                            const int* __restrict__ qei, int Eq,
                            const float* __restrict__ W31, const float* __restrict__ b31,
                            const float* __restrict__ W32, const float* __restrict__ b32,
                            const float* __restrict__ W41, const float* __restrict__ b41,
                            const float* __restrict__ W42, const float* __restrict__ b42,
                            const float* __restrict__ linW, const float* __restrict__ linb,
                            float* __restrict__ out)
{
    __shared__ float qx[512], uu[512], vv[512];
    __shared__ float hr[EQ_MAX * 64], me[EQ_MAX * 64];
    __shared__ __align__(16) float W2s[64 * 64];
    __shared__ float ps[2048];
    __shared__ int   qes[EQ_MAX], qet[EQ_MAX];
    __shared__ float emb[64];

    int tid = threadIdx.x;
    if (Eq > EQ_MAX) Eq = EQ_MAX;

    if (tid < Eq) { qes[tid] = qei[tid]; qet[tid] = qei[Eq + tid]; }

    {
        int idx = tid & 511, half = tid >> 9;
        float s = 0.f;
#pragma unroll
        for (int bk = half * 32; bk < half * 32 + 32; ++bk)
            s += qsums[bk * 512 + idx];
        ps[tid] = s;
    }
    __syncthreads();
    if (tid < 512) {
        int r = tid >> 6;
        int cc = qcnt[r];
        float tot = ps[tid] + ps[512 + tid];
        qx[tid] = (cc > 0) ? tot / (float)cc : 0.f;
    }
    __syncthreads();

    for (int layer = 0; layer < 2; ++layer) {
        const float* W1p = layer ? W41 : W31;
        const float* b1p = layer ? b41 : b31;
        const float* W2p = layer ? W42 : W32;
        const float* b2p = layer ? b42 : b32;

        *(fv4*)&W2s[tid * 4] = *(const fv4*)&W2p[tid * 4];

        {
            int idx = tid & 511, half = tid >> 9;
            int t = idx >> 6, c = idx & 63;
            float su = 0.f, sv = 0.f;
#pragma unroll 8
            for (int d = half * 32; d < half * 32 + 32; ++d) {
                float hv = qx[t * 64 + d];
                float a = W1p[d * 64 + c];
                float b = W1p[(d + 64) * 64 + c];
                su += hv * (a - b);
                sv += hv * b;
            }
            ps[tid] = su;
            ps[1024 + tid] = sv;
        }
        __syncthreads();
        if (tid < 512) {
            int c = tid & 63;
            uu[tid] = ps[tid] + ps[512 + tid] + b1p[c];
            vv[tid] = ps[1024 + tid] + ps[1536 + tid];
        }
        __syncthreads();

        for (int idx = tid; idx < Eq * 64; idx += 1024) {
            int e = idx >> 6, c = idx & 63;
            hr[idx] = fmaxf(uu[qet[e] * 64 + c] + vv[qes[e] * 64 + c], 0.f);
        }
        __syncthreads();

        {
            int c = tid & 63, e0 = tid >> 6;
            for (int e = e0; e < Eq; e += 16) {
                float acc = 0.f;
#pragma unroll 8
                for (int j = 0; j < 64; ++j)
                    acc += hr[e * 64 + j] * W2s[j * 64 + c];
                me[e * 64 + c] = acc;
            }
        }
        __syncthreads();

        if (tid < 512) {
            int t = tid >> 6, c = tid & 63;
            float a = -INFINITY;
            for (int e = 0; e < Eq; ++e)
                if (qet[e] == t) a = fmaxf(a, me[e * 64 + c]);
            float vout = (a == -INFINITY) ? 0.f : (a + b2p[c]);
            qx[tid] = fmaxf(vout, 0.f);
        }
        __syncthreads();
    }

    if (tid < 64) {
        float s = 0.f;
        for (int r = 0; r < 8; ++r) s += qx[r * 64 + tid];
        emb[tid] = s;
    }
    __syncthreads();
    if (tid < 8) {
        float o = linb[tid];
        for (int c = 0; c < 64; ++c) o += emb[c] * linW[c * 8 + tid];
        out[tid] = o;
    }
}

// ---------------------------------------------------------------------------
extern "C" void kernel_launch(void* const* d_in, const int* in_sizes, int n_in,
                              void* d_out, int out_size, void* d_ws, size_t ws_size,
                              hipStream_t stream)
{
    const float* x    = (const float*)d_in[0];
    const float* pos  = (const float*)d_in[1];
    const int*   ei   = (const int*)d_in[2];
    const int*   lbl  = (const int*)d_in[3];
    const int*   qei  = (const int*)d_in[4];
    const float* W11 = (const float*)d_in[5];
    const float* b11 = (const float*)d_in[6];
    const float* W12 = (const float*)d_in[7];
    const float* b12 = (const float*)d_in[8];
    const float* W21 = (const float*)d_in[9];
    const float* b21 = (const float*)d_in[10];
    const float* W22 = (const float*)d_in[11];
    const float* b22 = (const float*)d_in[12];
    const float* W31 = (const float*)d_in[13];
    const float* b31 = (const float*)d_in[14];
    const float* W32 = (const float*)d_in[15];
    const float* b32 = (const float*)d_in[16];
    const float* W41 = (const float*)d_in[17];
    const float* b41 = (const float*)d_in[18];
    const float* W42 = (const float*)d_in[19];
    const float* b42 = (const float*)d_in[20];
    const float* linW = (const float*)d_in[21];
    const float* linb = (const float*)d_in[22];

    int N  = in_sizes[0] / 16;          // 100000
    int Eq = in_sizes[4] / 2;           // 32
    const int* src = ei;                // row 0 = src; tgt = repeat(arange(N),16)

    size_t NH = (size_t)N * HDIM;
    unsigned short* hbf = (unsigned short*)d_ws;   // fp16 N*64 (h1 fallback / U2 fused)
    unsigned short* Ub  = hbf + NH;                // fp16 N*64
    unsigned short* Vb  = Ub + NH;                 // fp16 N*64
    unsigned short* w2h1 = Vb + NH;
    unsigned short* w2l1 = w2h1 + 4096;
    unsigned short* w2h2 = w2l1 + 4096;
    unsigned short* w2l2 = w2h2 + 4096;
    unsigned short* wph  = w2l2 + 4096;            // 8192
    unsigned short* wpl  = wph + 8192;             // 8192
    float* qsums = (float*)(wpl + 8192);           // QBANKS banks x 512
    int*   qcnt  = (int*)(qsums + QBANKS * 512);
    unsigned short* V2 = (unsigned short*)(qcnt + 8);   // extra NH (fused path)

    size_t needBytes = ((char*)(V2 + NH)) - ((char*)d_ws);
    bool fused = ws_size >= needBytes;
    unsigned short* U2 = hbf;

    (void)hipMemsetAsync(qsums, 0, QBANKS * 512 * sizeof(float) + 8 * sizeof(int), stream);

    int nTiles      = N / 16;           // pre_mfma tiles (6250)
    int edgeBlocks  = N / 32;           // edge blocks, 32 nodes each (3125)
    int mainBlocks  = 2048;

    // conv1 (pre1 + fused prep + label histogram)
    pre1_kernel<<<mainBlocks + 32, 256, 0, stream>>>(
        x, pos, W11, b11, Ub, Vb, N, mainBlocks,
        W12, W22, W21, w2h1, w2l1, w2h2, w2l2, wph, wpl, lbl, qcnt);

    if (fused) {
        // conv1 edge + fused conv2-layer1 MFMA -> U2/V2 (h1 never global)
        edge_mfma_kernel<2><<<edgeBlocks, 256, 0, stream>>>(
            Ub, Vb, src, w2h1, w2l1, b12, nullptr, lbl, qsums,
            wph, wpl, b21, U2, V2);
        // conv2 edge + fused region-sum pooling
        edge_mfma_kernel<1><<<edgeBlocks, 256, 0, stream>>>(
            U2, V2, src, w2h2, w2l2, b22, nullptr, lbl, qsums,
            nullptr, nullptr, nullptr, nullptr, nullptr);
    } else {
        edge_mfma_kernel<0><<<edgeBlocks, 256, 0, stream>>>(
            Ub, Vb, src, w2h1, w2l1, b12, hbf, lbl, qsums,
            nullptr, nullptr, nullptr, nullptr, nullptr);
        pre_mfma_kernel<<<1563, 256, 0, stream>>>(hbf, wph, wpl, b21, Ub, Vb, nTiles);
        edge_mfma_kernel<1><<<edgeBlocks, 256, 0, stream>>>(
            Ub, Vb, src, w2h2, w2l2, b22, hbf, lbl, qsums,
            nullptr, nullptr, nullptr, nullptr, nullptr);
    }
    // quotient tail
    tail_kernel<<<1, 1024, 0, stream>>>(qsums, qcnt, qei, Eq,
                                        W31, b31, W32, b32,
                                        W41, b41, W42, b42,
                                        linW, linb, (float*)d_out);
}